// Round 2
// baseline (306.517 us; speedup 1.0000x reference)
//
#include <hip/hip_runtime.h>
#include <hip/hip_bf16.h>
#include <stdint.h>

// ---------------------------------------------------------------------------
// RG-LRU block: T=8192, D_MODEL=768, D_RNN=1024, KW=4.
// Round 8: attack the cache-fill bandwidth bound (tile traffic at ~5.6 TB/s
// was pacing every GEMM round):
//  - BM=256 tiles, 512 threads (8 waves, 2Mx4N), 2-phase counted-vmcnt
//    double-buffer retained (verified structure, bigger parameters).
//    Arithmetic intensity doubles -> tile traffic halves.
//  - grid flipped: blockIdx.x = N-panel so wgid%8 puts one B column-panel
//    per XCD (B panel 0.4-1MB -> L2-resident re-reads).
//  - conv returns to shift-reuse (BK=32, A halo staged once, 4 B shift
//    tiles) inside the 256-row template: A traffic /4, B panel 1MB in L2.
//  - XOR bank swizzles (pre-swizzled global src + swizzled read) retained.
// ---------------------------------------------------------------------------

#define T_LEN 8192
#define DM 768
#define DR 1024
#define NC 128   // scan chunks
#define CL 64    // chunk length

typedef __bf16 bf16x8 __attribute__((ext_vector_type(8)));
typedef float  f32x4  __attribute__((ext_vector_type(4)));

#define AS1 __attribute__((address_space(1)))
#define AS3 __attribute__((address_space(3)))

__device__ __forceinline__ void cp16_g2l(const void* g, void* l) {
    __builtin_amdgcn_global_load_lds((const AS1 void*)g, (AS3 void*)l, 16, 0, 0);
}

__device__ __forceinline__ float gelu_tanh(float x) {
    const float inner = 0.7978845608028654f * (x + 0.044715f * x * x * x);
    return 0.5f * x * (1.f + tanhf(inner));
}

// ---------------------------------------------------------------------------
// Pipelined dense GEMM: C[m,n] = sum_k A[m,k]*B[n,k] (+bias[n]).
// BM=256, BK=64, 512 threads (8 waves as 2M x 4N).
// LDS rows are 64 elements = 8 16B chunks; chunk slot s at row r holds global
// chunk s ^ (r & 7)  -> bank-balanced wave64 ds_read_b128 (measured 0 confl).
// EPI: 0 = fp32 +bias; 1 = bf16 +bias; 2 = split (gelu->Cv / shift->D2).
// Grid: x = N/BN (XCD-pinned B panel), y = M/256.
// ---------------------------------------------------------------------------
template<int BN, int EPI>
__global__ __launch_bounds__(512, 2)
void gemm_mfma(const __hip_bfloat16* __restrict__ A,
               const __hip_bfloat16* __restrict__ B,
               const float* __restrict__ bias,
               void* __restrict__ Cv,
               int K, int lda, int N,
               __hip_bfloat16* __restrict__ D2)
{
    constexpr int NI  = BN / 64;           // n-frags per wave (4 or 2)
    constexpr int NLD = 4 + NI;            // global_load_lds per thread per tile
    __shared__ __bf16 As[2][256 * 64];
    __shared__ __bf16 Bs[2][BN * 64];

    const int tid  = threadIdx.x;
    const int lane = tid & 63;
    const int wave = tid >> 6;
    const int    n0 = blockIdx.x * BN;
    const size_t m0 = (size_t)blockIdx.y * 256;
    const int wm = (wave >> 2) * 128;          // 2 wave-rows
    const int wn = (wave & 3) * (BN / 4);      // 4 wave-cols

    f32x4 acc[8][NI];
#pragma unroll
    for (int i = 0; i < 8; ++i)
#pragma unroll
        for (int j = 0; j < NI; ++j)
            acc[i][j] = f32x4{0.f, 0.f, 0.f, 0.f};

    const int frow = lane & 15;
    const int fq   = lane >> 4;

    auto stage = [&](int buf, int k0) {
        // A tile: 256 rows x 8 chunks = 2048 chunks
#pragma unroll
        for (int q = 0; q < 4; ++q) {
            const int lin = q * 512 + tid;
            const int rr  = lin >> 3;
            const int gc  = (lin & 7) ^ (rr & 7);
            cp16_g2l(A + (m0 + rr) * (size_t)lda + k0 + gc * 8, &As[buf][lin * 8]);
        }
        // B tile: BN rows x 8 chunks
#pragma unroll
        for (int q = 0; q < NI; ++q) {
            const int lin = q * 512 + tid;
            const int rr  = lin >> 3;
            const int gc  = (lin & 7) ^ (rr & 7);
            cp16_g2l(B + (size_t)(n0 + rr) * K + k0 + gc * 8, &Bs[buf][lin * 8]);
        }
    };

    const int nt = K / 64;
    stage(0, 0);
    int cur = 0;
    for (int t = 0; t < nt; ++t) {
        if (t + 1 < nt) {
            stage(cur ^ 1, (t + 1) * 64);
            asm volatile("s_waitcnt vmcnt(%0)" :: "n"(NLD) : "memory");
        } else {
            asm volatile("s_waitcnt vmcnt(0)" ::: "memory");
        }
        __builtin_amdgcn_sched_barrier(0);
        __builtin_amdgcn_s_barrier();          // buf[cur] staged for all waves
        __builtin_amdgcn_sched_barrier(0);

#pragma unroll
        for (int ks = 0; ks < 2; ++ks) {
            bf16x8 af[8], bfr[NI];
#pragma unroll
            for (int mi = 0; mi < 8; ++mi) {
                const int R = wm + mi * 16 + frow;
                af[mi] = *(const bf16x8*)&As[cur][R * 64 + (((ks * 4 + fq) ^ (R & 7)) * 8)];
            }
#pragma unroll
            for (int ni = 0; ni < NI; ++ni) {
                const int R = wn + ni * 16 + frow;
                bfr[ni] = *(const bf16x8*)&Bs[cur][R * 64 + (((ks * 4 + fq) ^ (R & 7)) * 8)];
            }
            asm volatile("s_waitcnt lgkmcnt(0)" ::: "memory");
            __builtin_amdgcn_sched_barrier(0);
#pragma unroll
            for (int mi = 0; mi < 8; ++mi)
#pragma unroll
                for (int ni = 0; ni < NI; ++ni)
                    acc[mi][ni] = __builtin_amdgcn_mfma_f32_16x16x32_bf16(
                        af[mi], bfr[ni], acc[mi][ni], 0, 0, 0);
        }
        __builtin_amdgcn_s_barrier();          // buf[cur] free for overwrite
        __builtin_amdgcn_sched_barrier(0);
        cur ^= 1;
    }

    // C/D layout: col = lane&15, row = (lane>>4)*4 + reg
    const int er = fq * 4;
    const int ec = frow;
#pragma unroll
    for (int ni = 0; ni < NI; ++ni) {
        const int n = n0 + wn + ni * 16 + ec;
        const float bv = bias ? bias[n] : 0.f;
#pragma unroll
        for (int mi = 0; mi < 8; ++mi) {
#pragma unroll
            for (int r2 = 0; r2 < 4; ++r2) {
                const size_t m = m0 + wm + mi * 16 + er + r2;
                const float v = acc[mi][ni][r2] + bv;
                if (EPI == 0) {
                    ((float*)Cv)[m * (size_t)N + n] = v;
                } else if (EPI == 1) {
                    ((__hip_bfloat16*)Cv)[m * (size_t)N + n] = __float2bfloat16(v);
                } else {
                    if (n < 1024)
                        ((__hip_bfloat16*)Cv)[m * 1024 + n] = __float2bfloat16(gelu_tanh(v));
                    else
                        D2[(m + 3) * 1024 + (n - 1024)] = __float2bfloat16(v);
                }
            }
        }
    }
}

// ---------------------------------------------------------------------------
// Conv with shift reuse, 256-row tiles: bc[t,o] = sum_s sum_i
//   W[o][s*1024+i] * bbp[t+s][i].  BK=32 per col-tile; A halo (260 rows x 32)
// staged ONCE + 4 B shift tiles (128 x 32); 4 shifts x 16 MFMA per wave per
// barrier-pair; 32 k-iters.  2-phase counted-vmcnt double-buffer.
// 32-wide rows = 4 chunks; slot s at row r holds chunk s ^ ((r>>1)&3).
// Grid: x = 1024/128 = 8 (XCD-pinned 1MB B panel), y = 32.
// ---------------------------------------------------------------------------
__global__ __launch_bounds__(512, 2)
void conv_mfma(const __hip_bfloat16* __restrict__ bbp,
               const __hip_bfloat16* __restrict__ W,
               __hip_bfloat16* __restrict__ C)
{
    __shared__ __bf16 As[2][260 * 32];     // 32.5 KB halo tiles
    __shared__ __bf16 Bs[2][4 * 128 * 32]; // 64 KB, 4 shift tiles x2

    const int tid  = threadIdx.x;
    const int lane = tid & 63;
    const int wave = tid >> 6;
    const int    n0 = blockIdx.x * 128;
    const size_t m0 = (size_t)blockIdx.y * 256;
    const int wm = (wave >> 2) * 128;
    const int wn = (wave & 3) * 32;

    f32x4 acc[8][2];
#pragma unroll
    for (int i = 0; i < 8; ++i)
#pragma unroll
        for (int j = 0; j < 2; ++j)
            acc[i][j] = f32x4{0.f, 0.f, 0.f, 0.f};

    const int frow = lane & 15;
    const int fq   = lane >> 4;

    auto stage = [&](int buf, int kc) {
        // A halo: 260 rows x 4 chunks = 1040 chunks (2*512 + 16)
#pragma unroll
        for (int q = 0; q < 2; ++q) {
            const int lin = q * 512 + tid;
            const int rr  = lin >> 2;
            const int gc  = (lin & 3) ^ ((rr >> 1) & 3);
            cp16_g2l(bbp + (m0 + rr) * 1024 + kc + gc * 8, &As[buf][lin * 8]);
        }
        if (tid < 16) {
            const int lin = 1024 + tid;
            const int rr  = lin >> 2;
            const int gc  = (lin & 3) ^ ((rr >> 1) & 3);
            cp16_g2l(bbp + (m0 + rr) * 1024 + kc + gc * 8, &As[buf][lin * 8]);
        }
        // B: 4 shift tiles, each 128 rows x 4 chunks = 512 chunks
#pragma unroll
        for (int s = 0; s < 4; ++s) {
            const int rr = tid >> 2;
            const int gc = (tid & 3) ^ ((rr >> 1) & 3);
            cp16_g2l(W + (size_t)(n0 + rr) * 4096 + s * 1024 + kc + gc * 8,
                     &Bs[buf][s * 4096 + tid * 8]);
        }
    };

    stage(0, 0);
    int cur = 0;
    for (int t = 0; t < 32; ++t) {
        if (t + 1 < 32) {
            stage(cur ^ 1, (t + 1) * 32);
            asm volatile("s_waitcnt vmcnt(6)" ::: "memory");
        } else {
            asm volatile("s_waitcnt vmcnt(0)" ::: "memory");
        }
        __builtin_amdgcn_sched_barrier(0);
        __builtin_amdgcn_s_barrier();
        __builtin_amdgcn_sched_barrier(0);

#pragma unroll
        for (int s = 0; s < 4; ++s) {
            bf16x8 af[8], bfr[2];
#pragma unroll
            for (int mi = 0; mi < 8; ++mi) {
                const int R = wm + mi * 16 + frow + s;       // shifted row
                af[mi] = *(const bf16x8*)&As[cur][R * 32 + ((fq ^ ((R >> 1) & 3)) * 8)];
            }
#pragma unroll
            for (int ni = 0; ni < 2; ++ni) {
                const int R = wn + ni * 16 + frow;
                bfr[ni] = *(const bf16x8*)&Bs[cur][s * 4096 + R * 32 + ((fq ^ ((R >> 1) & 3)) * 8)];
            }
            asm volatile("s_waitcnt lgkmcnt(0)" ::: "memory");
            __builtin_amdgcn_sched_barrier(0);
#pragma unroll
            for (int mi = 0; mi < 8; ++mi)
#pragma unroll
                for (int ni = 0; ni < 2; ++ni)
                    acc[mi][ni] = __builtin_amdgcn_mfma_f32_16x16x32_bf16(
                        af[mi], bfr[ni], acc[mi][ni], 0, 0, 0);
        }
        __builtin_amdgcn_s_barrier();
        __builtin_amdgcn_sched_barrier(0);
        cur ^= 1;
    }

    const int er = fq * 4;
    const int ec = frow;
#pragma unroll
    for (int ni = 0; ni < 2; ++ni) {
        const int n = n0 + wn + ni * 16 + ec;
#pragma unroll
        for (int mi = 0; mi < 8; ++mi)
#pragma unroll
            for (int r2 = 0; r2 < 4; ++r2) {
                const size_t m = m0 + wm + mi * 16 + er + r2;
                C[m * 1024 + n] = __float2bfloat16(acc[mi][ni][r2]);
            }
    }
}

// One prep kernel: xb, w1b, w_rgb, w_outb conversions + conv repack + bbp pad zero.
#define PREP_X   6291456            // 8192*768
#define PREP_W1  (PREP_X + 1572864) // + 2048*768
#define PREP_WRG (PREP_W1 + 2097152)// + 2048*1024
#define PREP_WO  (PREP_WRG + 786432)// + 768*1024
#define PREP_CW  (PREP_WO + 4194304)// + 1024*4096
#define PREP_TOT (PREP_CW + 3072)   // + pad rows
__global__ void prep_kernel(const float* __restrict__ x, const float* __restrict__ w1,
                            const float* __restrict__ w_rg, const float* __restrict__ w_out,
                            const float* __restrict__ conv_w,
                            __hip_bfloat16* __restrict__ xb, __hip_bfloat16* __restrict__ w1b,
                            __hip_bfloat16* __restrict__ w_rgb, __hip_bfloat16* __restrict__ w_outb,
                            __hip_bfloat16* __restrict__ wbigb, __hip_bfloat16* __restrict__ bbp)
{
    const int idx = blockIdx.x * 256 + threadIdx.x;
    if (idx < PREP_X) {
        xb[idx] = __float2bfloat16(x[idx]);
    } else if (idx < PREP_W1) {
        const int i = idx - PREP_X;  w1b[i] = __float2bfloat16(w1[i]);
    } else if (idx < PREP_WRG) {
        const int i = idx - PREP_W1; w_rgb[i] = __float2bfloat16(w_rg[i]);
    } else if (idx < PREP_WO) {
        const int i = idx - PREP_WRG; w_outb[i] = __float2bfloat16(w_out[i]);
    } else if (idx < PREP_CW) {
        const int n = idx - PREP_WO;
        const int o = n >> 12, r = n & 4095, k = r >> 10, i = r & 1023;
        wbigb[n] = __float2bfloat16(conv_w[o * 4096 + i * 4 + k]);
    } else {
        bbp[idx - PREP_CW] = __float2bfloat16(0.f);
    }
}

// Gates recomputed inline from g_pre (T x 2048 bf16) + bc (bf16):
__global__ void scan_pass1(const __hip_bfloat16* __restrict__ gp,
                           const __hip_bfloat16* __restrict__ bc,
                           const float* __restrict__ Lambda,
                           float* __restrict__ ch, float* __restrict__ ca)
{
    const int c = blockIdx.y * 256 + threadIdx.x;
    const int j = blockIdx.x;
    const float cl = -8.f * log1pf(expf(Lambda[c]));
    float h = 0.f, ap = 1.f;
    const int t0 = j * CL;
    for (int tt = 0; tt < CL; ++tt) {
        const int t = t0 + tt;
        const long gi = (long)t * 2048 + c;
        const float ig = 1.f / (1.f + expf(-__bfloat162float(gp[gi])));
        const float rg = 1.f / (1.f + expf(-__bfloat162float(gp[gi + 1024])));
        const float a  = expf(cl * rg);
        const float gx = sqrtf(fmaxf(0.f, 1.f - a * a)) * ig *
                         __bfloat162float(bc[(long)t * 1024 + c]);
        h  = fmaf(a, h, gx);
        ap *= a;
    }
    ch[j * 1024 + c] = h;
    ca[j * 1024 + c] = ap;
}

__global__ void scan_combine(float* __restrict__ ch, const float* __restrict__ ca)
{
    const int c = blockIdx.x * 256 + threadIdx.x;
    float carry = 0.f;
    for (int j = 0; j < NC; ++j) {
        const float hj = ch[j * 1024 + c];
        const float aj = ca[j * 1024 + c];
        ch[j * 1024 + c] = carry;
        carry = fmaf(aj, carry, hj);
    }
}

// Rescan with carry; z = ab * y -> bf16 (zb aliases bc: same-element RMW per thread).
__global__ void scan_pass2(const __hip_bfloat16* __restrict__ gp, const __hip_bfloat16* bc,
                           const float* __restrict__ Lambda,
                           const float* __restrict__ carry_in,
                           const __hip_bfloat16* __restrict__ ab,
                           __hip_bfloat16* zb)
{
    const int c = blockIdx.y * 256 + threadIdx.x;
    const int j = blockIdx.x;
    const float cl = -8.f * log1pf(expf(Lambda[c]));
    float h = carry_in[j * 1024 + c];
    const int t0 = j * CL;
    for (int tt = 0; tt < CL; ++tt) {
        const int t = t0 + tt;
        const long gi = (long)t * 2048 + c;
        const long bi = (long)t * 1024 + c;
        const float ig = 1.f / (1.f + expf(-__bfloat162float(gp[gi])));
        const float rg = 1.f / (1.f + expf(-__bfloat162float(gp[gi + 1024])));
        const float a  = expf(cl * rg);
        const float gx = sqrtf(fmaxf(0.f, 1.f - a * a)) * ig * __bfloat162float(bc[bi]);
        h = fmaf(a, h, gx);
        zb[bi] = __float2bfloat16(__bfloat162float(ab[bi]) * h);
    }
}

extern "C" void kernel_launch(void* const* d_in, const int* in_sizes, int n_in,
                              void* d_out, int out_size, void* d_ws, size_t ws_size,
                              hipStream_t stream)
{
    const float* x      = (const float*)d_in[0];
    const float* w1     = (const float*)d_in[1];
    const float* b1     = (const float*)d_in[2];
    const float* conv_w = (const float*)d_in[3];
    const float* w_rg   = (const float*)d_in[4];
    const float* b_rg   = (const float*)d_in[5];
    const float* w_out  = (const float*)d_in[6];
    const float* b_out  = (const float*)d_in[7];
    const float* Lambda = (const float*)d_in[8];
    float* out = (float*)d_out;
    (void)in_sizes; (void)n_in; (void)out_size; (void)ws_size;

    // ---- workspace layout (~110 MB) ----
    char* p = (char*)d_ws;
    auto alloc = [&](size_t bytes) { char* r = p; p += (bytes + 255) & ~255ULL; return r; };
    __hip_bfloat16* gpre  = (__hip_bfloat16*)alloc(8192ULL * 2048 * 2); // 32 MB
    __hip_bfloat16* ab    = (__hip_bfloat16*)alloc(8192ULL * 1024 * 2); // 16 MB
    __hip_bfloat16* bbp   = (__hip_bfloat16*)alloc(8200ULL * 1024 * 2); // 16.8 MB
    __hip_bfloat16* bcb   = (__hip_bfloat16*)alloc(8192ULL * 1024 * 2); // 16 MB (later zb)
    __hip_bfloat16* wbigb = (__hip_bfloat16*)alloc(1024ULL * 4096 * 2); // 8 MB
    __hip_bfloat16* xb    = (__hip_bfloat16*)alloc(8192ULL * 768 * 2);  // 12 MB
    __hip_bfloat16* w1b   = (__hip_bfloat16*)alloc(2048ULL * 768 * 2);  // 3 MB
    __hip_bfloat16* w_rgb = (__hip_bfloat16*)alloc(2048ULL * 1024 * 2); // 4 MB
    __hip_bfloat16* w_outb= (__hip_bfloat16*)alloc(768ULL * 1024 * 2);  // 1.5 MB
    float*          chv   = (float*)alloc(NC * 1024ULL * 4);
    float*          cav   = (float*)alloc(NC * 1024ULL * 4);
    __hip_bfloat16* zb    = bcb;   // overlay

    prep_kernel<<<PREP_TOT / 256, 256, 0, stream>>>(x, w1, w_rg, w_out, conv_w,
                                                    xb, w1b, w_rgb, w_outb, wbigb, bbp);

    // h = x @ w1.T + b1, fused split: ab = bf16(gelu), bbp = bf16 (rows +3)
    {
        dim3 grid(2048 / 256, T_LEN / 256);
        gemm_mfma<256, 2><<<grid, 512, 0, stream>>>(xb, w1b, b1, ab, DM, DM, 2048, bbp);
    }

    // bc = causal conv (shift-reuse, 256-row tiles) -> bf16
    {
        dim3 grid(1024 / 128, T_LEN / 256);
        conv_mfma<<<grid, 512, 0, stream>>>(bbp, wbigb, bcb);
    }

    // g_pre = bc @ w_rg.T + b_rg -> bf16
    {
        dim3 grid(2048 / 256, T_LEN / 256);
        gemm_mfma<256, 1><<<grid, 512, 0, stream>>>(bcb, w_rgb, b_rg, gpre, DR, DR, 2048, nullptr);
    }

    // chunked scan with fused gates; z = ab*y -> bf16 (overlays bcb)
    {
        dim3 gs(NC, DR / 256);
        scan_pass1<<<gs, 256, 0, stream>>>(gpre, bcb, Lambda, chv, cav);
        scan_combine<<<DR / 256, 256, 0, stream>>>(chv, cav);
        scan_pass2<<<gs, 256, 0, stream>>>(gpre, bcb, Lambda, chv, ab, zb);
    }

    // out = z @ w_out.T + b_out -> fp32
    {
        dim3 grid(DM / 128, T_LEN / 256);
        gemm_mfma<128, 0><<<grid, 512, 0, stream>>>(zb, w_outb, b_out, out, DR, DR, DM, nullptr);
    }
}

// Round 3
// 298.868 us; speedup vs baseline: 1.0256x; 1.0256x over previous
//
#include <hip/hip_runtime.h>
#include <hip/hip_bf16.h>
#include <stdint.h>

// ---------------------------------------------------------------------------
// RG-LRU block: T=8192, D_MODEL=768, D_RNN=1024, KW=4.
// Round 9: revert to R1 (round-7) K-loop structure exactly (best verified:
// 128x{128,64} tiles, 256 thr, 2 blocks/CU, 2-phase counted-vmcnt dbuf,
// conv folded as SHIFT K=4096 GEMM).  New in this round:
//  - LDS-transposed coalesced epilogue: acc -> swizzled LDS (reusing the
//    32KB As staging buffers) -> b128 readback -> 16B/lane global stores in
//    256B contiguous row-runs.  Replaces 64 scalar 2B stores per thread
//    (theory: partial-sector scattered writes of the 32MiB outputs were
//    pacing gemm1/gemm3 at ~390 GB/s).
//  - scan_pass1/2 vectorized to bf16x2 loads/stores (2 cols per thread).
// ---------------------------------------------------------------------------

#define T_LEN 8192
#define DM 768
#define DR 1024
#define NC 128   // scan chunks
#define CL 64    // chunk length

typedef __bf16 bf16x8 __attribute__((ext_vector_type(8)));
typedef __bf16 bf16x2 __attribute__((ext_vector_type(2)));
typedef float  f32x4  __attribute__((ext_vector_type(4)));

#define AS1 __attribute__((address_space(1)))
#define AS3 __attribute__((address_space(3)))

__device__ __forceinline__ void cp16_g2l(const void* g, void* l) {
    __builtin_amdgcn_global_load_lds((const AS1 void*)g, (AS3 void*)l, 16, 0, 0);
}

__device__ __forceinline__ float gelu_tanh(float x) {
    const float inner = 0.7978845608028654f * (x + 0.044715f * x * x * x);
    return 0.5f * x * (1.f + tanhf(inner));
}

__device__ __forceinline__ __bf16 f2b(float v) {
    __hip_bfloat16 h = __float2bfloat16(v);
    return *reinterpret_cast<__bf16*>(&h);
}
__device__ __forceinline__ float b2f(__bf16 v) {
    __hip_bfloat16 h = *reinterpret_cast<__hip_bfloat16*>(&v);
    return __bfloat162float(h);
}

// ---------------------------------------------------------------------------
// Pipelined dense GEMM: C[m,n] = sum_k A[m,k]*B[n,k] (+bias[n]).
// BM=128, BK=64, 256 threads (4 waves, 2Mx2N).  K % 64 == 0.
// SHIFT=true (conv mode): A row += k0>>10, A col = k0 & 1023 (lda=1024).
// LDS rows are 64 elements = 8 16B chunks; chunk slot s at row r holds global
// chunk s ^ (r & 7)  -> bank-balanced wave64 ds_read_b128.
// EPI: 0 = fp32 +bias (BN=64); 1 = bf16 +bias; 2 = split (gelu->Cv / D2).
// Epilogue goes through LDS (reusing As) for coalesced 16B stores.
// ---------------------------------------------------------------------------
template<int BN, int EPI, bool SHIFT>
__global__ __launch_bounds__(256, 2)
void gemm_mfma(const __hip_bfloat16* __restrict__ A,
               const __hip_bfloat16* __restrict__ B,
               const float* __restrict__ bias,
               void* __restrict__ Cv,
               int K, int lda, int N,
               __hip_bfloat16* __restrict__ D2)
{
    constexpr int NI  = BN / 32;           // n-frags per wave (4 or 2)
    constexpr int NLD = 4 + NI;            // global_load_lds per thread per tile
    __shared__ __bf16 As[2][128 * 64];
    __shared__ __bf16 Bs[2][BN * 64];

    const int tid  = threadIdx.x;
    const int lane = tid & 63;
    const int wave = tid >> 6;
    const size_t m0 = (size_t)blockIdx.x * 128;
    const int    n0 = blockIdx.y * BN;
    const int wm = (wave >> 1) * 64;
    const int wn = (wave & 1) * (BN / 2);

    f32x4 acc[4][NI];
#pragma unroll
    for (int i = 0; i < 4; ++i)
#pragma unroll
        for (int j = 0; j < NI; ++j)
            acc[i][j] = f32x4{0.f, 0.f, 0.f, 0.f};

    const int frow = lane & 15;
    const int fq   = lane >> 4;

    auto stage = [&](int buf, int k0) {
        // A tile: 128 rows x 8 chunks = 1024 chunks
#pragma unroll
        for (int q = 0; q < 4; ++q) {
            const int lin = q * 256 + tid;
            const int rr  = lin >> 3;
            const int gc  = (lin & 7) ^ (rr & 7);
            const size_t ar = m0 + rr + (SHIFT ? (size_t)(k0 >> 10) : 0);
            const int    ac = SHIFT ? (k0 & 1023) : k0;
            cp16_g2l(A + ar * (size_t)lda + ac + gc * 8, &As[buf][lin * 8]);
        }
        // B tile: BN rows x 8 chunks
#pragma unroll
        for (int q = 0; q < NI; ++q) {
            const int lin = q * 256 + tid;
            const int rr  = lin >> 3;
            const int gc  = (lin & 7) ^ (rr & 7);
            cp16_g2l(B + (size_t)(n0 + rr) * K + k0 + gc * 8, &Bs[buf][lin * 8]);
        }
    };

    const int nt = K / 64;
    stage(0, 0);
    int cur = 0;
    for (int t = 0; t < nt; ++t) {
        if (t + 1 < nt) {
            stage(cur ^ 1, (t + 1) * 64);
            // wait only for tile t (the NLD loads just issued may stay in flight)
            asm volatile("s_waitcnt vmcnt(%0)" :: "n"(NLD) : "memory");
        } else {
            asm volatile("s_waitcnt vmcnt(0)" ::: "memory");
        }
        __builtin_amdgcn_sched_barrier(0);
        __builtin_amdgcn_s_barrier();          // buf[cur] staged for all waves
        __builtin_amdgcn_sched_barrier(0);

        bf16x8 af[2][4], bfr[2][NI];
#pragma unroll
        for (int ks = 0; ks < 2; ++ks) {
#pragma unroll
            for (int mi = 0; mi < 4; ++mi) {
                const int R = wm + mi * 16 + frow;
                af[ks][mi] = *(const bf16x8*)&As[cur][R * 64 + (((ks * 4 + fq) ^ (R & 7)) * 8)];
            }
#pragma unroll
            for (int ni = 0; ni < NI; ++ni) {
                const int R = wn + ni * 16 + frow;
                bfr[ks][ni] = *(const bf16x8*)&Bs[cur][R * 64 + (((ks * 4 + fq) ^ (R & 7)) * 8)];
            }
        }
        asm volatile("s_waitcnt lgkmcnt(0)" ::: "memory");  // my reads serviced
        __builtin_amdgcn_sched_barrier(0);
        __builtin_amdgcn_s_barrier();          // buf[cur] free for overwrite
        __builtin_amdgcn_sched_barrier(0);

#pragma unroll
        for (int ks = 0; ks < 2; ++ks)
#pragma unroll
            for (int mi = 0; mi < 4; ++mi)
#pragma unroll
                for (int ni = 0; ni < NI; ++ni)
                    acc[mi][ni] = __builtin_amdgcn_mfma_f32_16x16x32_bf16(
                        af[ks][mi], bfr[ks][ni], acc[mi][ni], 0, 0, 0);
        cur ^= 1;
    }

    // ---- epilogue: acc -> swizzled LDS -> coalesced 16B/lane global stores.
    // C/D frag layout: col = lane&15, row = (lane>>4)*4 + reg.
    __syncthreads();
    const int er = fq * 4;
    const int ec = frow;

    if (EPI == 0) {
        // fp32 tile 128 x BN(=64): 32 KB, exactly the As space.
        float* Cl = (float*)&As[0][0];
#pragma unroll
        for (int ni = 0; ni < NI; ++ni) {
            const int cc = wn + ni * 16 + ec;
            const float bv = bias ? bias[n0 + cc] : 0.f;
#pragma unroll
            for (int mi = 0; mi < 4; ++mi)
#pragma unroll
                for (int r2 = 0; r2 < 4; ++r2) {
                    const int R = wm + mi * 16 + er + r2;
                    Cl[R * 64 + ((((cc >> 2) ^ (R & 7)) << 2) | (cc & 3))] =
                        acc[mi][ni][r2] + bv;
                }
        }
        __syncthreads();
        float* outp = (float*)Cv;
#pragma unroll
        for (int p = 0; p < 8; ++p) {
            const int R   = (tid >> 4) + p * 16;
            const int chn = tid & 15;
            const f32x4 v = *(const f32x4*)&Cl[R * 64 + ((chn ^ (R & 7)) << 2)];
            *(f32x4*)&outp[(m0 + R) * (size_t)N + n0 + chn * 4] = v;
        }
    } else {
        // bf16 tile 128 x BN(=128): 32 KB, exactly the As space.
        __bf16* Cl = (__bf16*)&As[0][0];
        const bool ahalf = (EPI == 2) && (n0 < 1024);   // block-uniform
#pragma unroll
        for (int ni = 0; ni < NI; ++ni) {
            const int cc = wn + ni * 16 + ec;
            const float bv = bias ? bias[n0 + cc] : 0.f;
#pragma unroll
            for (int mi = 0; mi < 4; ++mi)
#pragma unroll
                for (int r2 = 0; r2 < 4; ++r2) {
                    const int R = wm + mi * 16 + er + r2;
                    float v = acc[mi][ni][r2] + bv;
                    if (EPI == 2 && ahalf) v = gelu_tanh(v);
                    Cl[R * 128 + ((((cc >> 3) ^ (R & 7)) << 3) | (cc & 7))] = f2b(v);
                }
        }
        __syncthreads();
#pragma unroll
        for (int p = 0; p < 8; ++p) {
            const int R   = (tid >> 4) + p * 16;
            const int chn = tid & 15;
            const bf16x8 v = *(const bf16x8*)&Cl[R * 128 + ((chn ^ (R & 7)) << 3)];
            if (EPI == 1) {
                *(bf16x8*)((__bf16*)Cv + (m0 + R) * (size_t)N + n0 + chn * 8) = v;
            } else if (n0 < 1024) {
                *(bf16x8*)((__bf16*)Cv + (m0 + R) * 1024 + n0 + chn * 8) = v;
            } else {
                *(bf16x8*)((__bf16*)D2 + (m0 + R + 3) * 1024 + (n0 - 1024) + chn * 8) = v;
            }
        }
    }
}

// One prep kernel: xb, w1b, w_rgb, w_outb conversions + conv repack + bbp pad zero.
#define PREP_X   6291456            // 8192*768
#define PREP_W1  (PREP_X + 1572864) // + 2048*768
#define PREP_WRG (PREP_W1 + 2097152)// + 2048*1024
#define PREP_WO  (PREP_WRG + 786432)// + 768*1024
#define PREP_CW  (PREP_WO + 4194304)// + 1024*4096
#define PREP_TOT (PREP_CW + 3072)   // + pad rows
__global__ void prep_kernel(const float* __restrict__ x, const float* __restrict__ w1,
                            const float* __restrict__ w_rg, const float* __restrict__ w_out,
                            const float* __restrict__ conv_w,
                            __hip_bfloat16* __restrict__ xb, __hip_bfloat16* __restrict__ w1b,
                            __hip_bfloat16* __restrict__ w_rgb, __hip_bfloat16* __restrict__ w_outb,
                            __hip_bfloat16* __restrict__ wbigb, __hip_bfloat16* __restrict__ bbp)
{
    const int idx = blockIdx.x * 256 + threadIdx.x;
    if (idx < PREP_X) {
        xb[idx] = __float2bfloat16(x[idx]);
    } else if (idx < PREP_W1) {
        const int i = idx - PREP_X;  w1b[i] = __float2bfloat16(w1[i]);
    } else if (idx < PREP_WRG) {
        const int i = idx - PREP_W1; w_rgb[i] = __float2bfloat16(w_rg[i]);
    } else if (idx < PREP_WO) {
        const int i = idx - PREP_WRG; w_outb[i] = __float2bfloat16(w_out[i]);
    } else if (idx < PREP_CW) {
        const int n = idx - PREP_WO;
        const int o = n >> 12, r = n & 4095, k = r >> 10, i = r & 1023;
        wbigb[n] = __float2bfloat16(conv_w[o * 4096 + i * 4 + k]);
    } else {
        bbp[idx - PREP_CW] = __float2bfloat16(0.f);
    }
}

// Gates recomputed inline from g_pre (T x 2048 bf16) + bc (bf16); 2 cols/thread.
__global__ void scan_pass1(const __hip_bfloat16* __restrict__ gp,
                           const __hip_bfloat16* __restrict__ bc,
                           const float* __restrict__ Lambda,
                           float* __restrict__ ch, float* __restrict__ ca)
{
    const int c = (blockIdx.y * 256 + threadIdx.x) * 2;
    const int j = blockIdx.x;
    const float cl0 = -8.f * log1pf(expf(Lambda[c]));
    const float cl1 = -8.f * log1pf(expf(Lambda[c + 1]));
    float h0 = 0.f, h1 = 0.f, ap0 = 1.f, ap1 = 1.f;
    const int t0 = j * CL;
    for (int tt = 0; tt < CL; ++tt) {
        const int t = t0 + tt;
        const bf16x2 igv = *(const bf16x2*)&gp[(long)t * 2048 + c];
        const bf16x2 rgv = *(const bf16x2*)&gp[(long)t * 2048 + 1024 + c];
        const bf16x2 bcv = *(const bf16x2*)&bc[(long)t * 1024 + c];
        const float ig0 = 1.f / (1.f + expf(-b2f(igv[0])));
        const float ig1 = 1.f / (1.f + expf(-b2f(igv[1])));
        const float rg0 = 1.f / (1.f + expf(-b2f(rgv[0])));
        const float rg1 = 1.f / (1.f + expf(-b2f(rgv[1])));
        const float a0  = expf(cl0 * rg0);
        const float a1  = expf(cl1 * rg1);
        const float gx0 = sqrtf(fmaxf(0.f, 1.f - a0 * a0)) * ig0 * b2f(bcv[0]);
        const float gx1 = sqrtf(fmaxf(0.f, 1.f - a1 * a1)) * ig1 * b2f(bcv[1]);
        h0 = fmaf(a0, h0, gx0);  ap0 *= a0;
        h1 = fmaf(a1, h1, gx1);  ap1 *= a1;
    }
    ch[j * 1024 + c] = h0;  ch[j * 1024 + c + 1] = h1;
    ca[j * 1024 + c] = ap0; ca[j * 1024 + c + 1] = ap1;
}

__global__ void scan_combine(float* __restrict__ ch, const float* __restrict__ ca)
{
    const int c = blockIdx.x * 256 + threadIdx.x;
    float carry = 0.f;
    for (int j = 0; j < NC; ++j) {
        const float hj = ch[j * 1024 + c];
        const float aj = ca[j * 1024 + c];
        ch[j * 1024 + c] = carry;
        carry = fmaf(aj, carry, hj);
    }
}

// Rescan with carry; z = ab * y -> bf16 (zb aliases bc: same-element RMW per thread).
__global__ void scan_pass2(const __hip_bfloat16* __restrict__ gp, const __hip_bfloat16* bc,
                           const float* __restrict__ Lambda,
                           const float* __restrict__ carry_in,
                           const __hip_bfloat16* __restrict__ ab,
                           __hip_bfloat16* zb)
{
    const int c = (blockIdx.y * 256 + threadIdx.x) * 2;
    const int j = blockIdx.x;
    const float cl0 = -8.f * log1pf(expf(Lambda[c]));
    const float cl1 = -8.f * log1pf(expf(Lambda[c + 1]));
    float h0 = carry_in[j * 1024 + c];
    float h1 = carry_in[j * 1024 + c + 1];
    const int t0 = j * CL;
    for (int tt = 0; tt < CL; ++tt) {
        const int t = t0 + tt;
        const long bi = (long)t * 1024 + c;
        const bf16x2 igv = *(const bf16x2*)&gp[(long)t * 2048 + c];
        const bf16x2 rgv = *(const bf16x2*)&gp[(long)t * 2048 + 1024 + c];
        const bf16x2 bcv = *(const bf16x2*)&bc[bi];
        const bf16x2 abv = *(const bf16x2*)&ab[bi];
        const float ig0 = 1.f / (1.f + expf(-b2f(igv[0])));
        const float ig1 = 1.f / (1.f + expf(-b2f(igv[1])));
        const float rg0 = 1.f / (1.f + expf(-b2f(rgv[0])));
        const float rg1 = 1.f / (1.f + expf(-b2f(rgv[1])));
        const float a0  = expf(cl0 * rg0);
        const float a1  = expf(cl1 * rg1);
        const float gx0 = sqrtf(fmaxf(0.f, 1.f - a0 * a0)) * ig0 * b2f(bcv[0]);
        const float gx1 = sqrtf(fmaxf(0.f, 1.f - a1 * a1)) * ig1 * b2f(bcv[1]);
        h0 = fmaf(a0, h0, gx0);
        h1 = fmaf(a1, h1, gx1);
        bf16x2 o;
        o[0] = f2b(b2f(abv[0]) * h0);
        o[1] = f2b(b2f(abv[1]) * h1);
        *(bf16x2*)&zb[bi] = o;
    }
}

extern "C" void kernel_launch(void* const* d_in, const int* in_sizes, int n_in,
                              void* d_out, int out_size, void* d_ws, size_t ws_size,
                              hipStream_t stream)
{
    const float* x      = (const float*)d_in[0];
    const float* w1     = (const float*)d_in[1];
    const float* b1     = (const float*)d_in[2];
    const float* conv_w = (const float*)d_in[3];
    const float* w_rg   = (const float*)d_in[4];
    const float* b_rg   = (const float*)d_in[5];
    const float* w_out  = (const float*)d_in[6];
    const float* b_out  = (const float*)d_in[7];
    const float* Lambda = (const float*)d_in[8];
    float* out = (float*)d_out;
    (void)in_sizes; (void)n_in; (void)out_size; (void)ws_size;

    // ---- workspace layout (~110 MB) ----
    char* p = (char*)d_ws;
    auto alloc = [&](size_t bytes) { char* r = p; p += (bytes + 255) & ~255ULL; return r; };
    __hip_bfloat16* gpre  = (__hip_bfloat16*)alloc(8192ULL * 2048 * 2); // 32 MB
    __hip_bfloat16* ab    = (__hip_bfloat16*)alloc(8192ULL * 1024 * 2); // 16 MB
    __hip_bfloat16* bbp   = (__hip_bfloat16*)alloc(8200ULL * 1024 * 2); // 16.8 MB
    __hip_bfloat16* bcb   = (__hip_bfloat16*)alloc(8192ULL * 1024 * 2); // 16 MB (later zb)
    __hip_bfloat16* wbigb = (__hip_bfloat16*)alloc(1024ULL * 4096 * 2); // 8 MB
    __hip_bfloat16* xb    = (__hip_bfloat16*)alloc(8192ULL * 768 * 2);  // 12 MB
    __hip_bfloat16* w1b   = (__hip_bfloat16*)alloc(2048ULL * 768 * 2);  // 3 MB
    __hip_bfloat16* w_rgb = (__hip_bfloat16*)alloc(2048ULL * 1024 * 2); // 4 MB
    __hip_bfloat16* w_outb= (__hip_bfloat16*)alloc(768ULL * 1024 * 2);  // 1.5 MB
    float*          chv   = (float*)alloc(NC * 1024ULL * 4);
    float*          cav   = (float*)alloc(NC * 1024ULL * 4);
    __hip_bfloat16* zb    = bcb;   // overlay

    prep_kernel<<<PREP_TOT / 256, 256, 0, stream>>>(x, w1, w_rg, w_out, conv_w,
                                                    xb, w1b, w_rgb, w_outb, wbigb, bbp);

    // h = x @ w1.T + b1, fused split: ab = bf16(gelu), bbp = bf16 (rows +3)
    {
        dim3 grid(T_LEN / 128, 2048 / 128);
        gemm_mfma<128, 2, false><<<grid, 256, 0, stream>>>(xb, w1b, b1, ab, DM, DM, 2048, bbp);
    }

    // bc = causal conv as one K=4096 GEMM (shift folded into A row offset)
    {
        dim3 grid(T_LEN / 128, 1024 / 128);
        gemm_mfma<128, 1, true><<<grid, 256, 0, stream>>>(bbp, wbigb, nullptr, bcb, 4096, 1024, 1024, nullptr);
    }

    // g_pre = bc @ w_rg.T + b_rg -> bf16
    {
        dim3 grid(T_LEN / 128, 2048 / 128);
        gemm_mfma<128, 1, false><<<grid, 256, 0, stream>>>(bcb, w_rgb, b_rg, gpre, DR, DR, 2048, nullptr);
    }

    // chunked scan with fused gates; z = ab*y -> bf16 (overlays bcb)
    {
        dim3 gs(NC, DR / 512);
        scan_pass1<<<gs, 256, 0, stream>>>(gpre, bcb, Lambda, chv, cav);
        scan_combine<<<DR / 256, 256, 0, stream>>>(chv, cav);
        scan_pass2<<<gs, 256, 0, stream>>>(gpre, bcb, Lambda, chv, ab, zb);
    }

    // out = z @ w_out.T + b_out -> fp32
    {
        dim3 grid(T_LEN / 128, DM / 64);
        gemm_mfma<64, 0, false><<<grid, 256, 0, stream>>>(zb, w_outb, b_out, out, DR, DR, DM, nullptr);
    }
}

// Round 4
// 283.994 us; speedup vs baseline: 1.0793x; 1.0524x over previous
//
#include <hip/hip_runtime.h>
#include <hip/hip_bf16.h>
#include <stdint.h>

// ---------------------------------------------------------------------------
// RG-LRU block: T=8192, D_MODEL=768, D_RNN=1024, KW=4.
// Round 10: residency/TLP attack.  Evidence: per-iter slot time ~4550 cyc for
// 2-round kernels (gemm1/gemm3) vs ~1300 for the fully-resident conv; all
// pipes idle (Mfma 11%, HBM 8%, VALU 18%, occ 22%).  -> latency-bound, thin
// TLP.  Changes:
//  - BK=32, single 32KB smem arena (As 16KB + Bs 16KB, dbuf) -> 4 blocks/CU
//    (__launch_bounds__(256,4)); gemm1/gemm3/out grids fully resident in ONE
//    round; 16 waves/CU for cross-block latency hiding.
//  - counted-vmcnt 2-phase pipeline, XOR swizzles, LDS epilogue retained.
//  - s_setprio(1) around MFMA cluster (wave role diversity now exists).
//  - scans reverted to R1-verified scalar form.
// ---------------------------------------------------------------------------

#define T_LEN 8192
#define DM 768
#define DR 1024
#define NC 128   // scan chunks
#define CL 64    // chunk length

typedef __bf16 bf16x8 __attribute__((ext_vector_type(8)));
typedef float  f32x4  __attribute__((ext_vector_type(4)));

#define AS1 __attribute__((address_space(1)))
#define AS3 __attribute__((address_space(3)))

__device__ __forceinline__ void cp16_g2l(const void* g, void* l) {
    __builtin_amdgcn_global_load_lds((const AS1 void*)g, (AS3 void*)l, 16, 0, 0);
}

__device__ __forceinline__ float gelu_tanh(float x) {
    const float inner = 0.7978845608028654f * (x + 0.044715f * x * x * x);
    return 0.5f * x * (1.f + tanhf(inner));
}

__device__ __forceinline__ __bf16 f2b(float v) {
    __hip_bfloat16 h = __float2bfloat16(v);
    return *reinterpret_cast<__bf16*>(&h);
}

// ---------------------------------------------------------------------------
// Pipelined dense GEMM: C[m,n] = sum_k A[m,k]*B[n,k] (+bias[n]).
// BM=128, BK=32, 256 threads (4 waves, 2Mx2N), 4 blocks/CU.  K % 32 == 0.
// SHIFT=true (conv mode): A row += k0>>10, A col = k0 & 1023 (lda=1024).
// LDS rows are 32 elements = 4 16B chunks; chunk slot s at row r holds global
// chunk s ^ ((r>>1) & 3)  -> bank-balanced wave64 ds_read_b128 (0 measured
// conflicts in the round-0 conv kernel with this exact scheme).
// EPI: 0 = fp32 +bias (BN=64); 1 = bf16 +bias; 2 = split (gelu->Cv / D2).
// Epilogue reuses the 32KB smem arena for coalesced 16B stores.
// ---------------------------------------------------------------------------
template<int BN, int EPI, bool SHIFT>
__global__ __launch_bounds__(256, 4)
void gemm_mfma(const __hip_bfloat16* __restrict__ A,
               const __hip_bfloat16* __restrict__ B,
               const float* __restrict__ bias,
               void* __restrict__ Cv,
               int K, int lda, int N,
               __hip_bfloat16* __restrict__ D2)
{
    constexpr int NI  = BN / 32;           // n-frags per wave (4 or 2)
    constexpr int BLD = (BN * 4) / 256;    // B cp16 per thread (2 or 1)
    constexpr int NLD = 2 + BLD;           // cp16 per thread per tile
    __shared__ __align__(16) unsigned char smem[32768];
    __bf16* Asb = (__bf16*)smem;            // [2][128*32]
    __bf16* Bsb = (__bf16*)(smem + 16384);  // [2][BN*32]

    const int tid  = threadIdx.x;
    const int lane = tid & 63;
    const int wave = tid >> 6;
    const size_t m0 = (size_t)blockIdx.x * 128;
    const int    n0 = blockIdx.y * BN;
    const int wm = (wave >> 1) * 64;
    const int wn = (wave & 1) * (BN / 2);

    f32x4 acc[4][NI];
#pragma unroll
    for (int i = 0; i < 4; ++i)
#pragma unroll
        for (int j = 0; j < NI; ++j)
            acc[i][j] = f32x4{0.f, 0.f, 0.f, 0.f};

    const int frow = lane & 15;
    const int fq   = lane >> 4;             // chunk index 0..3 within 32-wide row

    auto stage = [&](int buf, int k0) {
        // A tile: 128 rows x 4 chunks = 512 chunks
#pragma unroll
        for (int q = 0; q < 2; ++q) {
            const int lin = q * 256 + tid;
            const int rr  = lin >> 2;
            const int gc  = (lin & 3) ^ ((rr >> 1) & 3);
            const size_t ar = m0 + rr + (SHIFT ? (size_t)(k0 >> 10) : 0);
            const int    ac = SHIFT ? (k0 & 1023) : k0;
            cp16_g2l(A + ar * (size_t)lda + ac + gc * 8, Asb + buf * 4096 + lin * 8);
        }
        // B tile: BN rows x 4 chunks
#pragma unroll
        for (int q = 0; q < BLD; ++q) {
            const int lin = q * 256 + tid;
            const int rr  = lin >> 2;
            const int gc  = (lin & 3) ^ ((rr >> 1) & 3);
            cp16_g2l(B + (size_t)(n0 + rr) * K + k0 + gc * 8,
                     Bsb + buf * (BN * 32) + lin * 8);
        }
    };

    const int nt = K / 32;
    stage(0, 0);
    int cur = 0;
    for (int t = 0; t < nt; ++t) {
        if (t + 1 < nt) {
            stage(cur ^ 1, (t + 1) * 32);
            // wait only for tile t (the NLD loads just issued stay in flight)
            asm volatile("s_waitcnt vmcnt(%0)" :: "n"(NLD) : "memory");
        } else {
            asm volatile("s_waitcnt vmcnt(0)" ::: "memory");
        }
        __builtin_amdgcn_sched_barrier(0);
        __builtin_amdgcn_s_barrier();          // buf[cur] staged for all waves
        __builtin_amdgcn_sched_barrier(0);

        bf16x8 af[4], bfr[NI];
#pragma unroll
        for (int mi = 0; mi < 4; ++mi) {
            const int R = wm + mi * 16 + frow;
            af[mi] = *(const bf16x8*)&Asb[cur * 4096 + R * 32 + ((fq ^ ((R >> 1) & 3)) * 8)];
        }
#pragma unroll
        for (int ni = 0; ni < NI; ++ni) {
            const int R = wn + ni * 16 + frow;
            bfr[ni] = *(const bf16x8*)&Bsb[cur * (BN * 32) + R * 32 + ((fq ^ ((R >> 1) & 3)) * 8)];
        }
        asm volatile("s_waitcnt lgkmcnt(0)" ::: "memory");  // my reads serviced
        __builtin_amdgcn_sched_barrier(0);
        __builtin_amdgcn_s_barrier();          // buf[cur] free for overwrite
        __builtin_amdgcn_sched_barrier(0);

        __builtin_amdgcn_s_setprio(1);
#pragma unroll
        for (int mi = 0; mi < 4; ++mi)
#pragma unroll
            for (int ni = 0; ni < NI; ++ni)
                acc[mi][ni] = __builtin_amdgcn_mfma_f32_16x16x32_bf16(
                    af[mi], bfr[ni], acc[mi][ni], 0, 0, 0);
        __builtin_amdgcn_s_setprio(0);
        cur ^= 1;
    }

    // ---- epilogue: acc -> swizzled LDS -> coalesced 16B/lane global stores.
    // C/D frag layout: col = lane&15, row = (lane>>4)*4 + reg.
    __syncthreads();
    const int er = fq * 4;
    const int ec = frow;

    if (EPI == 0) {
        // fp32 tile 128 x BN(=64): 32 KB = the whole arena.
        float* Cl = (float*)smem;
#pragma unroll
        for (int ni = 0; ni < NI; ++ni) {
            const int cc = wn + ni * 16 + ec;
            const float bv = bias ? bias[n0 + cc] : 0.f;
#pragma unroll
            for (int mi = 0; mi < 4; ++mi)
#pragma unroll
                for (int r2 = 0; r2 < 4; ++r2) {
                    const int R = wm + mi * 16 + er + r2;
                    Cl[R * 64 + ((((cc >> 2) ^ (R & 7)) << 2) | (cc & 3))] =
                        acc[mi][ni][r2] + bv;
                }
        }
        __syncthreads();
        float* outp = (float*)Cv;
#pragma unroll
        for (int p = 0; p < 8; ++p) {
            const int R   = (tid >> 4) + p * 16;
            const int chn = tid & 15;
            const f32x4 v = *(const f32x4*)&Cl[R * 64 + ((chn ^ (R & 7)) << 2)];
            *(f32x4*)&outp[(m0 + R) * (size_t)N + n0 + chn * 4] = v;
        }
    } else {
        // bf16 tile 128 x BN(=128): 32 KB = the whole arena.
        __bf16* Cl = (__bf16*)smem;
        const bool ahalf = (EPI == 2) && (n0 < 1024);   // block-uniform
#pragma unroll
        for (int ni = 0; ni < NI; ++ni) {
            const int cc = wn + ni * 16 + ec;
            const float bv = bias ? bias[n0 + cc] : 0.f;
#pragma unroll
            for (int mi = 0; mi < 4; ++mi)
#pragma unroll
                for (int r2 = 0; r2 < 4; ++r2) {
                    const int R = wm + mi * 16 + er + r2;
                    float v = acc[mi][ni][r2] + bv;
                    if (EPI == 2 && ahalf) v = gelu_tanh(v);
                    Cl[R * 128 + ((((cc >> 3) ^ (R & 7)) << 3) | (cc & 7))] = f2b(v);
                }
        }
        __syncthreads();
#pragma unroll
        for (int p = 0; p < 8; ++p) {
            const int R   = (tid >> 4) + p * 16;
            const int chn = tid & 15;
            const bf16x8 v = *(const bf16x8*)&Cl[R * 128 + ((chn ^ (R & 7)) << 3)];
            if (EPI == 1) {
                *(bf16x8*)((__bf16*)Cv + (m0 + R) * (size_t)N + n0 + chn * 8) = v;
            } else if (n0 < 1024) {
                *(bf16x8*)((__bf16*)Cv + (m0 + R) * 1024 + n0 + chn * 8) = v;
            } else {
                *(bf16x8*)((__bf16*)D2 + (m0 + R + 3) * 1024 + (n0 - 1024) + chn * 8) = v;
            }
        }
    }
}

// One prep kernel: xb, w1b, w_rgb, w_outb conversions + conv repack + bbp pad zero.
#define PREP_X   6291456            // 8192*768
#define PREP_W1  (PREP_X + 1572864) // + 2048*768
#define PREP_WRG (PREP_W1 + 2097152)// + 2048*1024
#define PREP_WO  (PREP_WRG + 786432)// + 768*1024
#define PREP_CW  (PREP_WO + 4194304)// + 1024*4096
#define PREP_TOT (PREP_CW + 3072)   // + pad rows
__global__ void prep_kernel(const float* __restrict__ x, const float* __restrict__ w1,
                            const float* __restrict__ w_rg, const float* __restrict__ w_out,
                            const float* __restrict__ conv_w,
                            __hip_bfloat16* __restrict__ xb, __hip_bfloat16* __restrict__ w1b,
                            __hip_bfloat16* __restrict__ w_rgb, __hip_bfloat16* __restrict__ w_outb,
                            __hip_bfloat16* __restrict__ wbigb, __hip_bfloat16* __restrict__ bbp)
{
    const int idx = blockIdx.x * 256 + threadIdx.x;
    if (idx < PREP_X) {
        xb[idx] = __float2bfloat16(x[idx]);
    } else if (idx < PREP_W1) {
        const int i = idx - PREP_X;  w1b[i] = __float2bfloat16(w1[i]);
    } else if (idx < PREP_WRG) {
        const int i = idx - PREP_W1; w_rgb[i] = __float2bfloat16(w_rg[i]);
    } else if (idx < PREP_WO) {
        const int i = idx - PREP_WRG; w_outb[i] = __float2bfloat16(w_out[i]);
    } else if (idx < PREP_CW) {
        const int n = idx - PREP_WO;
        const int o = n >> 12, r = n & 4095, k = r >> 10, i = r & 1023;
        wbigb[n] = __float2bfloat16(conv_w[o * 4096 + i * 4 + k]);
    } else {
        bbp[idx - PREP_CW] = __float2bfloat16(0.f);
    }
}

// Gates recomputed inline from g_pre (T x 2048 bf16) + bc (bf16):
__global__ void scan_pass1(const __hip_bfloat16* __restrict__ gp,
                           const __hip_bfloat16* __restrict__ bc,
                           const float* __restrict__ Lambda,
                           float* __restrict__ ch, float* __restrict__ ca)
{
    const int c = blockIdx.y * 256 + threadIdx.x;
    const int j = blockIdx.x;
    const float cl = -8.f * log1pf(expf(Lambda[c]));
    float h = 0.f, ap = 1.f;
    const int t0 = j * CL;
    for (int tt = 0; tt < CL; ++tt) {
        const int t = t0 + tt;
        const long gi = (long)t * 2048 + c;
        const float ig = 1.f / (1.f + expf(-__bfloat162float(gp[gi])));
        const float rg = 1.f / (1.f + expf(-__bfloat162float(gp[gi + 1024])));
        const float a  = expf(cl * rg);
        const float gx = sqrtf(fmaxf(0.f, 1.f - a * a)) * ig *
                         __bfloat162float(bc[(long)t * 1024 + c]);
        h  = fmaf(a, h, gx);
        ap *= a;
    }
    ch[j * 1024 + c] = h;
    ca[j * 1024 + c] = ap;
}

__global__ void scan_combine(float* __restrict__ ch, const float* __restrict__ ca)
{
    const int c = blockIdx.x * 256 + threadIdx.x;
    float carry = 0.f;
    for (int j = 0; j < NC; ++j) {
        const float hj = ch[j * 1024 + c];
        const float aj = ca[j * 1024 + c];
        ch[j * 1024 + c] = carry;
        carry = fmaf(aj, carry, hj);
    }
}

// Rescan with carry; z = ab * y -> bf16 (zb aliases bc: same-element RMW per thread).
__global__ void scan_pass2(const __hip_bfloat16* __restrict__ gp, const __hip_bfloat16* bc,
                           const float* __restrict__ Lambda,
                           const float* __restrict__ carry_in,
                           const __hip_bfloat16* __restrict__ ab,
                           __hip_bfloat16* zb)
{
    const int c = blockIdx.y * 256 + threadIdx.x;
    const int j = blockIdx.x;
    const float cl = -8.f * log1pf(expf(Lambda[c]));
    float h = carry_in[j * 1024 + c];
    const int t0 = j * CL;
    for (int tt = 0; tt < CL; ++tt) {
        const int t = t0 + tt;
        const long gi = (long)t * 2048 + c;
        const long bi = (long)t * 1024 + c;
        const float ig = 1.f / (1.f + expf(-__bfloat162float(gp[gi])));
        const float rg = 1.f / (1.f + expf(-__bfloat162float(gp[gi + 1024])));
        const float a  = expf(cl * rg);
        const float gx = sqrtf(fmaxf(0.f, 1.f - a * a)) * ig * __bfloat162float(bc[bi]);
        h = fmaf(a, h, gx);
        zb[bi] = __float2bfloat16(__bfloat162float(ab[bi]) * h);
    }
}

extern "C" void kernel_launch(void* const* d_in, const int* in_sizes, int n_in,
                              void* d_out, int out_size, void* d_ws, size_t ws_size,
                              hipStream_t stream)
{
    const float* x      = (const float*)d_in[0];
    const float* w1     = (const float*)d_in[1];
    const float* b1     = (const float*)d_in[2];
    const float* conv_w = (const float*)d_in[3];
    const float* w_rg   = (const float*)d_in[4];
    const float* b_rg   = (const float*)d_in[5];
    const float* w_out  = (const float*)d_in[6];
    const float* b_out  = (const float*)d_in[7];
    const float* Lambda = (const float*)d_in[8];
    float* out = (float*)d_out;
    (void)in_sizes; (void)n_in; (void)out_size; (void)ws_size;

    // ---- workspace layout (~110 MB) ----
    char* p = (char*)d_ws;
    auto alloc = [&](size_t bytes) { char* r = p; p += (bytes + 255) & ~255ULL; return r; };
    __hip_bfloat16* gpre  = (__hip_bfloat16*)alloc(8192ULL * 2048 * 2); // 32 MB
    __hip_bfloat16* ab    = (__hip_bfloat16*)alloc(8192ULL * 1024 * 2); // 16 MB
    __hip_bfloat16* bbp   = (__hip_bfloat16*)alloc(8200ULL * 1024 * 2); // 16.8 MB
    __hip_bfloat16* bcb   = (__hip_bfloat16*)alloc(8192ULL * 1024 * 2); // 16 MB (later zb)
    __hip_bfloat16* wbigb = (__hip_bfloat16*)alloc(1024ULL * 4096 * 2); // 8 MB
    __hip_bfloat16* xb    = (__hip_bfloat16*)alloc(8192ULL * 768 * 2);  // 12 MB
    __hip_bfloat16* w1b   = (__hip_bfloat16*)alloc(2048ULL * 768 * 2);  // 3 MB
    __hip_bfloat16* w_rgb = (__hip_bfloat16*)alloc(2048ULL * 1024 * 2); // 4 MB
    __hip_bfloat16* w_outb= (__hip_bfloat16*)alloc(768ULL * 1024 * 2);  // 1.5 MB
    float*          chv   = (float*)alloc(NC * 1024ULL * 4);
    float*          cav   = (float*)alloc(NC * 1024ULL * 4);
    __hip_bfloat16* zb    = bcb;   // overlay

    prep_kernel<<<PREP_TOT / 256, 256, 0, stream>>>(x, w1, w_rg, w_out, conv_w,
                                                    xb, w1b, w_rgb, w_outb, wbigb, bbp);

    // h = x @ w1.T + b1, fused split: ab = bf16(gelu), bbp = bf16 (rows +3)
    {
        dim3 grid(T_LEN / 128, 2048 / 128);
        gemm_mfma<128, 2, false><<<grid, 256, 0, stream>>>(xb, w1b, b1, ab, DM, DM, 2048, bbp);
    }

    // bc = causal conv as one K=4096 GEMM (shift folded into A row offset)
    {
        dim3 grid(T_LEN / 128, 1024 / 128);
        gemm_mfma<128, 1, true><<<grid, 256, 0, stream>>>(bbp, wbigb, nullptr, bcb, 4096, 1024, 1024, nullptr);
    }

    // g_pre = bc @ w_rg.T + b_rg -> bf16
    {
        dim3 grid(T_LEN / 128, 2048 / 128);
        gemm_mfma<128, 1, false><<<grid, 256, 0, stream>>>(bcb, w_rgb, b_rg, gpre, DR, DR, 2048, nullptr);
    }

    // chunked scan with fused gates; z = ab*y -> bf16 (overlays bcb)
    {
        dim3 gs(NC, DR / 256);
        scan_pass1<<<gs, 256, 0, stream>>>(gpre, bcb, Lambda, chv, cav);
        scan_combine<<<DR / 256, 256, 0, stream>>>(chv, cav);
        scan_pass2<<<gs, 256, 0, stream>>>(gpre, bcb, Lambda, chv, ab, zb);
    }

    // out = z @ w_out.T + b_out -> fp32
    {
        dim3 grid(T_LEN / 128, DM / 64);
        gemm_mfma<64, 0, false><<<grid, 256, 0, stream>>>(zb, w_outb, b_out, out, DR, DR, DM, nullptr);
    }
}

// Round 5
// 273.295 us; speedup vs baseline: 1.1216x; 1.0391x over previous
//
#include <hip/hip_runtime.h>
#include <hip/hip_bf16.h>
#include <stdint.h>

// ---------------------------------------------------------------------------
// RG-LRU block: T=8192, D_MODEL=768, D_RNN=1024, KW=4.
// Round 11: R4 confirmed the TLP theory (Mfma 11->33%); conv is now the top
// dispatch (86.5us, FETCH 43MB = 4x A restage).  This round: conv shift-reuse
// inside the 4-blocks/CU structure:
//  - flat loop over (kc,s): 132-row A halo staged ONCE per kc (dbuf),
//    8KB B shift-tile staged per iter (dbuf).  LDS 32.5KB -> 4 blocks/CU.
//  - counted vmcnt: 2 per iter, 4 on the halo-prefetch iter (s==3).
//  - per-iter staged bytes 16KB -> 10.1KB avg for the same 16 MFMA; A's 4x
//    L2 refetch gone.
//  - gemm_mfma, scans, prep byte-identical to R4.
// ---------------------------------------------------------------------------

#define T_LEN 8192
#define DM 768
#define DR 1024
#define NC 128   // scan chunks
#define CL 64    // chunk length

typedef __bf16 bf16x8 __attribute__((ext_vector_type(8)));
typedef float  f32x4  __attribute__((ext_vector_type(4)));

#define AS1 __attribute__((address_space(1)))
#define AS3 __attribute__((address_space(3)))

__device__ __forceinline__ void cp16_g2l(const void* g, void* l) {
    __builtin_amdgcn_global_load_lds((const AS1 void*)g, (AS3 void*)l, 16, 0, 0);
}

__device__ __forceinline__ float gelu_tanh(float x) {
    const float inner = 0.7978845608028654f * (x + 0.044715f * x * x * x);
    return 0.5f * x * (1.f + tanhf(inner));
}

__device__ __forceinline__ __bf16 f2b(float v) {
    __hip_bfloat16 h = __float2bfloat16(v);
    return *reinterpret_cast<__bf16*>(&h);
}

// ---------------------------------------------------------------------------
// Pipelined dense GEMM: C[m,n] = sum_k A[m,k]*B[n,k] (+bias[n]).
// BM=128, BK=32, 256 threads (4 waves, 2Mx2N), 4 blocks/CU.  K % 32 == 0.
// LDS rows are 32 elements = 4 16B chunks; chunk slot s at row r holds global
// chunk s ^ ((r>>1) & 3)  -> bank-balanced wave64 ds_read_b128.
// EPI: 0 = fp32 +bias (BN=64); 1 = bf16 +bias; 2 = split (gelu->Cv / D2).
// Epilogue reuses the 32KB smem arena for coalesced 16B stores.
// ---------------------------------------------------------------------------
template<int BN, int EPI, bool SHIFT>
__global__ __launch_bounds__(256, 4)
void gemm_mfma(const __hip_bfloat16* __restrict__ A,
               const __hip_bfloat16* __restrict__ B,
               const float* __restrict__ bias,
               void* __restrict__ Cv,
               int K, int lda, int N,
               __hip_bfloat16* __restrict__ D2)
{
    constexpr int NI  = BN / 32;           // n-frags per wave (4 or 2)
    constexpr int BLD = (BN * 4) / 256;    // B cp16 per thread (2 or 1)
    constexpr int NLD = 2 + BLD;           // cp16 per thread per tile
    __shared__ __align__(16) unsigned char smem[32768];
    __bf16* Asb = (__bf16*)smem;            // [2][128*32]
    __bf16* Bsb = (__bf16*)(smem + 16384);  // [2][BN*32]

    const int tid  = threadIdx.x;
    const int lane = tid & 63;
    const int wave = tid >> 6;
    const size_t m0 = (size_t)blockIdx.x * 128;
    const int    n0 = blockIdx.y * BN;
    const int wm = (wave >> 1) * 64;
    const int wn = (wave & 1) * (BN / 2);

    f32x4 acc[4][NI];
#pragma unroll
    for (int i = 0; i < 4; ++i)
#pragma unroll
        for (int j = 0; j < NI; ++j)
            acc[i][j] = f32x4{0.f, 0.f, 0.f, 0.f};

    const int frow = lane & 15;
    const int fq   = lane >> 4;             // chunk index 0..3 within 32-wide row

    auto stage = [&](int buf, int k0) {
        // A tile: 128 rows x 4 chunks = 512 chunks
#pragma unroll
        for (int q = 0; q < 2; ++q) {
            const int lin = q * 256 + tid;
            const int rr  = lin >> 2;
            const int gc  = (lin & 3) ^ ((rr >> 1) & 3);
            const size_t ar = m0 + rr + (SHIFT ? (size_t)(k0 >> 10) : 0);
            const int    ac = SHIFT ? (k0 & 1023) : k0;
            cp16_g2l(A + ar * (size_t)lda + ac + gc * 8, Asb + buf * 4096 + lin * 8);
        }
        // B tile: BN rows x 4 chunks
#pragma unroll
        for (int q = 0; q < BLD; ++q) {
            const int lin = q * 256 + tid;
            const int rr  = lin >> 2;
            const int gc  = (lin & 3) ^ ((rr >> 1) & 3);
            cp16_g2l(B + (size_t)(n0 + rr) * K + k0 + gc * 8,
                     Bsb + buf * (BN * 32) + lin * 8);
        }
    };

    const int nt = K / 32;
    stage(0, 0);
    int cur = 0;
    for (int t = 0; t < nt; ++t) {
        if (t + 1 < nt) {
            stage(cur ^ 1, (t + 1) * 32);
            // wait only for tile t (the NLD loads just issued stay in flight)
            asm volatile("s_waitcnt vmcnt(%0)" :: "n"(NLD) : "memory");
        } else {
            asm volatile("s_waitcnt vmcnt(0)" ::: "memory");
        }
        __builtin_amdgcn_sched_barrier(0);
        __builtin_amdgcn_s_barrier();          // buf[cur] staged for all waves
        __builtin_amdgcn_sched_barrier(0);

        bf16x8 af[4], bfr[NI];
#pragma unroll
        for (int mi = 0; mi < 4; ++mi) {
            const int R = wm + mi * 16 + frow;
            af[mi] = *(const bf16x8*)&Asb[cur * 4096 + R * 32 + ((fq ^ ((R >> 1) & 3)) * 8)];
        }
#pragma unroll
        for (int ni = 0; ni < NI; ++ni) {
            const int R = wn + ni * 16 + frow;
            bfr[ni] = *(const bf16x8*)&Bsb[cur * (BN * 32) + R * 32 + ((fq ^ ((R >> 1) & 3)) * 8)];
        }
        asm volatile("s_waitcnt lgkmcnt(0)" ::: "memory");  // my reads serviced
        __builtin_amdgcn_sched_barrier(0);
        __builtin_amdgcn_s_barrier();          // buf[cur] free for overwrite
        __builtin_amdgcn_sched_barrier(0);

        __builtin_amdgcn_s_setprio(1);
#pragma unroll
        for (int mi = 0; mi < 4; ++mi)
#pragma unroll
            for (int ni = 0; ni < NI; ++ni)
                acc[mi][ni] = __builtin_amdgcn_mfma_f32_16x16x32_bf16(
                    af[mi], bfr[ni], acc[mi][ni], 0, 0, 0);
        __builtin_amdgcn_s_setprio(0);
        cur ^= 1;
    }

    // ---- epilogue: acc -> swizzled LDS -> coalesced 16B/lane global stores.
    // C/D frag layout: col = lane&15, row = (lane>>4)*4 + reg.
    __syncthreads();
    const int er = fq * 4;
    const int ec = frow;

    if (EPI == 0) {
        // fp32 tile 128 x BN(=64): 32 KB = the whole arena.
        float* Cl = (float*)smem;
#pragma unroll
        for (int ni = 0; ni < NI; ++ni) {
            const int cc = wn + ni * 16 + ec;
            const float bv = bias ? bias[n0 + cc] : 0.f;
#pragma unroll
            for (int mi = 0; mi < 4; ++mi)
#pragma unroll
                for (int r2 = 0; r2 < 4; ++r2) {
                    const int R = wm + mi * 16 + er + r2;
                    Cl[R * 64 + ((((cc >> 2) ^ (R & 7)) << 2) | (cc & 3))] =
                        acc[mi][ni][r2] + bv;
                }
        }
        __syncthreads();
        float* outp = (float*)Cv;
#pragma unroll
        for (int p = 0; p < 8; ++p) {
            const int R   = (tid >> 4) + p * 16;
            const int chn = tid & 15;
            const f32x4 v = *(const f32x4*)&Cl[R * 64 + ((chn ^ (R & 7)) << 2)];
            *(f32x4*)&outp[(m0 + R) * (size_t)N + n0 + chn * 4] = v;
        }
    } else {
        // bf16 tile 128 x BN(=128): 32 KB = the whole arena.
        __bf16* Cl = (__bf16*)smem;
        const bool ahalf = (EPI == 2) && (n0 < 1024);   // block-uniform
#pragma unroll
        for (int ni = 0; ni < NI; ++ni) {
            const int cc = wn + ni * 16 + ec;
            const float bv = bias ? bias[n0 + cc] : 0.f;
#pragma unroll
            for (int mi = 0; mi < 4; ++mi)
#pragma unroll
                for (int r2 = 0; r2 < 4; ++r2) {
                    const int R = wm + mi * 16 + er + r2;
                    float v = acc[mi][ni][r2] + bv;
                    if (EPI == 2 && ahalf) v = gelu_tanh(v);
                    Cl[R * 128 + ((((cc >> 3) ^ (R & 7)) << 3) | (cc & 7))] = f2b(v);
                }
        }
        __syncthreads();
#pragma unroll
        for (int p = 0; p < 8; ++p) {
            const int R   = (tid >> 4) + p * 16;
            const int chn = tid & 15;
            const bf16x8 v = *(const bf16x8*)&Cl[R * 128 + ((chn ^ (R & 7)) << 3)];
            if (EPI == 1) {
                *(bf16x8*)((__bf16*)Cv + (m0 + R) * (size_t)N + n0 + chn * 8) = v;
            } else if (n0 < 1024) {
                *(bf16x8*)((__bf16*)Cv + (m0 + R) * 1024 + n0 + chn * 8) = v;
            } else {
                *(bf16x8*)((__bf16*)D2 + (m0 + R + 3) * 1024 + (n0 - 1024) + chn * 8) = v;
            }
        }
    }
}

// ---------------------------------------------------------------------------
// Conv with shift reuse, 4 blocks/CU: bc[t,o] = sum_s sum_i
//   W[o][s*1024+i] * bbp[t+s][i].
// Flat loop u=0..127 over (kc=(u>>2)*32, s=u&3):
//  - A halo (132 rows x 32) staged once per kc into Ah dbuf (prefetched at
//    the s==3 iter of the previous kc).
//  - B shift tile (128 x 32) staged every iter into Bt dbuf.
//  - 16 MFMA per iter; A frags read with row offset +s.
// LDS = 2*8448 + 2*8192 = 32.5KB -> 4 blocks/CU.
// ---------------------------------------------------------------------------
__global__ __launch_bounds__(256, 4)
void conv_mfma(const __hip_bfloat16* __restrict__ bbp,
               const __hip_bfloat16* __restrict__ W,
               __hip_bfloat16* __restrict__ C)
{
    __shared__ __align__(16) unsigned char smem[33280];
    __bf16* Ah = (__bf16*)smem;             // [2][132*32]
    __bf16* Bt = (__bf16*)(smem + 16896);   // [2][128*32]

    const int tid  = threadIdx.x;
    const int lane = tid & 63;
    const int wave = tid >> 6;
    const size_t m0 = (size_t)blockIdx.x * 128;
    const int    n0 = blockIdx.y * 128;
    const int wm = (wave >> 1) * 64;
    const int wn = (wave & 1) * 64;

    f32x4 acc[4][4];
#pragma unroll
    for (int i = 0; i < 4; ++i)
#pragma unroll
        for (int j = 0; j < 4; ++j)
            acc[i][j] = f32x4{0.f, 0.f, 0.f, 0.f};

    const int frow = lane & 15;
    const int fq   = lane >> 4;

    auto stageA = [&](int abuf, int kc) {   // 132 rows x 4 chunks = 528 chunks
#pragma unroll
        for (int q = 0; q < 2; ++q) {
            const int lin = q * 256 + tid;
            const int rr  = lin >> 2;
            const int gc  = (lin & 3) ^ ((rr >> 1) & 3);
            cp16_g2l(bbp + (m0 + rr) * 1024 + kc + gc * 8, Ah + abuf * 4224 + lin * 8);
        }
        if (tid < 16) {
            const int lin = 512 + tid;
            const int rr  = lin >> 2;
            const int gc  = (lin & 3) ^ ((rr >> 1) & 3);
            cp16_g2l(bbp + (m0 + rr) * 1024 + kc + gc * 8, Ah + abuf * 4224 + lin * 8);
        }
    };
    auto stageB = [&](int bbuf, int u) {    // shift tile: 128 rows x 4 chunks
        const int s  = u & 3;
        const int kc = (u >> 2) * 32;
#pragma unroll
        for (int q = 0; q < 2; ++q) {
            const int lin = q * 256 + tid;
            const int rr  = lin >> 2;
            const int gc  = (lin & 3) ^ ((rr >> 1) & 3);
            cp16_g2l(W + (size_t)(n0 + rr) * 4096 + s * 1024 + kc + gc * 8,
                     Bt + bbuf * 4096 + lin * 8);
        }
    };

    stageA(0, 0);
    stageB(0, 0);
    int acur = 0, bcur = 0;
    for (int u = 0; u < 128; ++u) {
        const int s = u & 3;
        if (u + 1 < 128) {
            stageB(bcur ^ 1, u + 1);
            if (s == 3) {
                stageA(acur ^ 1, ((u >> 2) + 1) * 32);
                asm volatile("s_waitcnt vmcnt(4)" ::: "memory");
            } else {
                asm volatile("s_waitcnt vmcnt(2)" ::: "memory");
            }
        } else {
            asm volatile("s_waitcnt vmcnt(0)" ::: "memory");
        }
        __builtin_amdgcn_sched_barrier(0);
        __builtin_amdgcn_s_barrier();          // current buffers staged
        __builtin_amdgcn_sched_barrier(0);

        bf16x8 af[4], bfr[4];
#pragma unroll
        for (int mi = 0; mi < 4; ++mi) {
            const int R = wm + mi * 16 + frow + s;       // shifted halo row
            af[mi] = *(const bf16x8*)&Ah[acur * 4224 + R * 32 + ((fq ^ ((R >> 1) & 3)) * 8)];
        }
#pragma unroll
        for (int ni = 0; ni < 4; ++ni) {
            const int R = wn + ni * 16 + frow;
            bfr[ni] = *(const bf16x8*)&Bt[bcur * 4096 + R * 32 + ((fq ^ ((R >> 1) & 3)) * 8)];
        }
        asm volatile("s_waitcnt lgkmcnt(0)" ::: "memory");
        __builtin_amdgcn_sched_barrier(0);
        __builtin_amdgcn_s_barrier();          // buffers free for overwrite
        __builtin_amdgcn_sched_barrier(0);

        __builtin_amdgcn_s_setprio(1);
#pragma unroll
        for (int mi = 0; mi < 4; ++mi)
#pragma unroll
            for (int ni = 0; ni < 4; ++ni)
                acc[mi][ni] = __builtin_amdgcn_mfma_f32_16x16x32_bf16(
                    af[mi], bfr[ni], acc[mi][ni], 0, 0, 0);
        __builtin_amdgcn_s_setprio(0);

        bcur ^= 1;
        if (s == 3) acur ^= 1;
    }

    // ---- epilogue: bf16 tile 128x128 via swizzled LDS, coalesced stores.
    __syncthreads();
    const int er = fq * 4;
    const int ec = frow;
    __bf16* Cl = (__bf16*)smem;
#pragma unroll
    for (int ni = 0; ni < 4; ++ni) {
        const int cc = wn + ni * 16 + ec;
#pragma unroll
        for (int mi = 0; mi < 4; ++mi)
#pragma unroll
            for (int r2 = 0; r2 < 4; ++r2) {
                const int R = wm + mi * 16 + er + r2;
                Cl[R * 128 + ((((cc >> 3) ^ (R & 7)) << 3) | (cc & 7))] =
                    f2b(acc[mi][ni][r2]);
            }
    }
    __syncthreads();
#pragma unroll
    for (int p = 0; p < 8; ++p) {
        const int R   = (tid >> 4) + p * 16;
        const int chn = tid & 15;
        const bf16x8 v = *(const bf16x8*)&Cl[R * 128 + ((chn ^ (R & 7)) << 3)];
        *(bf16x8*)((__bf16*)C + (m0 + R) * 1024 + n0 + chn * 8) = v;
    }
}

// One prep kernel: xb, w1b, w_rgb, w_outb conversions + conv repack + bbp pad zero.
#define PREP_X   6291456            // 8192*768
#define PREP_W1  (PREP_X + 1572864) // + 2048*768
#define PREP_WRG (PREP_W1 + 2097152)// + 2048*1024
#define PREP_WO  (PREP_WRG + 786432)// + 768*1024
#define PREP_CW  (PREP_WO + 4194304)// + 1024*4096
#define PREP_TOT (PREP_CW + 3072)   // + pad rows
__global__ void prep_kernel(const float* __restrict__ x, const float* __restrict__ w1,
                            const float* __restrict__ w_rg, const float* __restrict__ w_out,
                            const float* __restrict__ conv_w,
                            __hip_bfloat16* __restrict__ xb, __hip_bfloat16* __restrict__ w1b,
                            __hip_bfloat16* __restrict__ w_rgb, __hip_bfloat16* __restrict__ w_outb,
                            __hip_bfloat16* __restrict__ wbigb, __hip_bfloat16* __restrict__ bbp)
{
    const int idx = blockIdx.x * 256 + threadIdx.x;
    if (idx < PREP_X) {
        xb[idx] = __float2bfloat16(x[idx]);
    } else if (idx < PREP_W1) {
        const int i = idx - PREP_X;  w1b[i] = __float2bfloat16(w1[i]);
    } else if (idx < PREP_WRG) {
        const int i = idx - PREP_W1; w_rgb[i] = __float2bfloat16(w_rg[i]);
    } else if (idx < PREP_WO) {
        const int i = idx - PREP_WRG; w_outb[i] = __float2bfloat16(w_out[i]);
    } else if (idx < PREP_CW) {
        const int n = idx - PREP_WO;
        const int o = n >> 12, r = n & 4095, k = r >> 10, i = r & 1023;
        wbigb[n] = __float2bfloat16(conv_w[o * 4096 + i * 4 + k]);
    } else {
        bbp[idx - PREP_CW] = __float2bfloat16(0.f);
    }
}

// Gates recomputed inline from g_pre (T x 2048 bf16) + bc (bf16):
__global__ void scan_pass1(const __hip_bfloat16* __restrict__ gp,
                           const __hip_bfloat16* __restrict__ bc,
                           const float* __restrict__ Lambda,
                           float* __restrict__ ch, float* __restrict__ ca)
{
    const int c = blockIdx.y * 256 + threadIdx.x;
    const int j = blockIdx.x;
    const float cl = -8.f * log1pf(expf(Lambda[c]));
    float h = 0.f, ap = 1.f;
    const int t0 = j * CL;
    for (int tt = 0; tt < CL; ++tt) {
        const int t = t0 + tt;
        const long gi = (long)t * 2048 + c;
        const float ig = 1.f / (1.f + expf(-__bfloat162float(gp[gi])));
        const float rg = 1.f / (1.f + expf(-__bfloat162float(gp[gi + 1024])));
        const float a  = expf(cl * rg);
        const float gx = sqrtf(fmaxf(0.f, 1.f - a * a)) * ig *
                         __bfloat162float(bc[(long)t * 1024 + c]);
        h  = fmaf(a, h, gx);
        ap *= a;
    }
    ch[j * 1024 + c] = h;
    ca[j * 1024 + c] = ap;
}

__global__ void scan_combine(float* __restrict__ ch, const float* __restrict__ ca)
{
    const int c = blockIdx.x * 256 + threadIdx.x;
    float carry = 0.f;
    for (int j = 0; j < NC; ++j) {
        const float hj = ch[j * 1024 + c];
        const float aj = ca[j * 1024 + c];
        ch[j * 1024 + c] = carry;
        carry = fmaf(aj, carry, hj);
    }
}

// Rescan with carry; z = ab * y -> bf16 (zb aliases bc: same-element RMW per thread).
__global__ void scan_pass2(const __hip_bfloat16* __restrict__ gp, const __hip_bfloat16* bc,
                           const float* __restrict__ Lambda,
                           const float* __restrict__ carry_in,
                           const __hip_bfloat16* __restrict__ ab,
                           __hip_bfloat16* zb)
{
    const int c = blockIdx.y * 256 + threadIdx.x;
    const int j = blockIdx.x;
    const float cl = -8.f * log1pf(expf(Lambda[c]));
    float h = carry_in[j * 1024 + c];
    const int t0 = j * CL;
    for (int tt = 0; tt < CL; ++tt) {
        const int t = t0 + tt;
        const long gi = (long)t * 2048 + c;
        const long bi = (long)t * 1024 + c;
        const float ig = 1.f / (1.f + expf(-__bfloat162float(gp[gi])));
        const float rg = 1.f / (1.f + expf(-__bfloat162float(gp[gi + 1024])));
        const float a  = expf(cl * rg);
        const float gx = sqrtf(fmaxf(0.f, 1.f - a * a)) * ig * __bfloat162float(bc[bi]);
        h = fmaf(a, h, gx);
        zb[bi] = __float2bfloat16(__bfloat162float(ab[bi]) * h);
    }
}

extern "C" void kernel_launch(void* const* d_in, const int* in_sizes, int n_in,
                              void* d_out, int out_size, void* d_ws, size_t ws_size,
                              hipStream_t stream)
{
    const float* x      = (const float*)d_in[0];
    const float* w1     = (const float*)d_in[1];
    const float* b1     = (const float*)d_in[2];
    const float* conv_w = (const float*)d_in[3];
    const float* w_rg   = (const float*)d_in[4];
    const float* b_rg   = (const float*)d_in[5];
    const float* w_out  = (const float*)d_in[6];
    const float* b_out  = (const float*)d_in[7];
    const float* Lambda = (const float*)d_in[8];
    float* out = (float*)d_out;
    (void)in_sizes; (void)n_in; (void)out_size; (void)ws_size;

    // ---- workspace layout (~110 MB) ----
    char* p = (char*)d_ws;
    auto alloc = [&](size_t bytes) { char* r = p; p += (bytes + 255) & ~255ULL; return r; };
    __hip_bfloat16* gpre  = (__hip_bfloat16*)alloc(8192ULL * 2048 * 2); // 32 MB
    __hip_bfloat16* ab    = (__hip_bfloat16*)alloc(8192ULL * 1024 * 2); // 16 MB
    __hip_bfloat16* bbp   = (__hip_bfloat16*)alloc(8200ULL * 1024 * 2); // 16.8 MB
    __hip_bfloat16* bcb   = (__hip_bfloat16*)alloc(8192ULL * 1024 * 2); // 16 MB (later zb)
    __hip_bfloat16* wbigb = (__hip_bfloat16*)alloc(1024ULL * 4096 * 2); // 8 MB
    __hip_bfloat16* xb    = (__hip_bfloat16*)alloc(8192ULL * 768 * 2);  // 12 MB
    __hip_bfloat16* w1b   = (__hip_bfloat16*)alloc(2048ULL * 768 * 2);  // 3 MB
    __hip_bfloat16* w_rgb = (__hip_bfloat16*)alloc(2048ULL * 1024 * 2); // 4 MB
    __hip_bfloat16* w_outb= (__hip_bfloat16*)alloc(768ULL * 1024 * 2);  // 1.5 MB
    float*          chv   = (float*)alloc(NC * 1024ULL * 4);
    float*          cav   = (float*)alloc(NC * 1024ULL * 4);
    __hip_bfloat16* zb    = bcb;   // overlay

    prep_kernel<<<PREP_TOT / 256, 256, 0, stream>>>(x, w1, w_rg, w_out, conv_w,
                                                    xb, w1b, w_rgb, w_outb, wbigb, bbp);

    // h = x @ w1.T + b1, fused split: ab = bf16(gelu), bbp = bf16 (rows +3)
    {
        dim3 grid(T_LEN / 128, 2048 / 128);
        gemm_mfma<128, 2, false><<<grid, 256, 0, stream>>>(xb, w1b, b1, ab, DM, DM, 2048, bbp);
    }

    // bc = causal conv (shift-reuse, A halo staged once per kc) -> bf16
    {
        dim3 grid(T_LEN / 128, 1024 / 128);
        conv_mfma<<<grid, 256, 0, stream>>>(bbp, wbigb, bcb);
    }

    // g_pre = bc @ w_rg.T + b_rg -> bf16
    {
        dim3 grid(T_LEN / 128, 2048 / 128);
        gemm_mfma<128, 1, false><<<grid, 256, 0, stream>>>(bcb, w_rgb, b_rg, gpre, DR, DR, 2048, nullptr);
    }

    // chunked scan with fused gates; z = ab*y -> bf16 (overlays bcb)
    {
        dim3 gs(NC, DR / 256);
        scan_pass1<<<gs, 256, 0, stream>>>(gpre, bcb, Lambda, chv, cav);
        scan_combine<<<DR / 256, 256, 0, stream>>>(chv, cav);
        scan_pass2<<<gs, 256, 0, stream>>>(gpre, bcb, Lambda, chv, ab, zb);
    }

    // out = z @ w_out.T + b_out -> fp32
    {
        dim3 grid(T_LEN / 128, DM / 64);
        gemm_mfma<64, 0, false><<<grid, 256, 0, stream>>>(zb, w_outb, b_out, out, DR, DR, DM, nullptr);
    }
}

// Round 6
// 272.175 us; speedup vs baseline: 1.1262x; 1.0041x over previous
//
#include <hip/hip_runtime.h>
#include <hip/hip_bf16.h>
#include <stdint.h>

// ---------------------------------------------------------------------------
// RG-LRU block: T=8192, D_MODEL=768, D_RNN=1024, KW=4.
// Round 12: conv barrier-cadence attack.  R5 evidence: conv at 882 TF = the
// ~900 TF ceiling of the 2-barrier-per-K-step structure (16 MFMA/wave per
// barrier-pair).  The 4 shift tiles of one kc read DISJOINT LDS -> no
// barriers between shifts.  New conv:
//  - per kc: stage 4 B shift tiles (32KB, dbuf) + 132-row halo (8.45KB,
//    single-buffered, prefetched post-barrier) -> 64 MFMA/wave per
//    barrier-pair (4x R5), counted vmcnt(8).
//  - LDS 72.3KB -> 2 blocks/CU kept (launch_bounds(256,2)).
//  - dense GEMMs / scans / prep byte-identical to R5.
// ---------------------------------------------------------------------------

#define T_LEN 8192
#define DM 768
#define DR 1024
#define NC 128   // scan chunks
#define CL 64    // chunk length

typedef __bf16 bf16x8 __attribute__((ext_vector_type(8)));
typedef float  f32x4  __attribute__((ext_vector_type(4)));

#define AS1 __attribute__((address_space(1)))
#define AS3 __attribute__((address_space(3)))

__device__ __forceinline__ void cp16_g2l(const void* g, void* l) {
    __builtin_amdgcn_global_load_lds((const AS1 void*)g, (AS3 void*)l, 16, 0, 0);
}

__device__ __forceinline__ float gelu_tanh(float x) {
    const float inner = 0.7978845608028654f * (x + 0.044715f * x * x * x);
    return 0.5f * x * (1.f + tanhf(inner));
}

__device__ __forceinline__ __bf16 f2b(float v) {
    __hip_bfloat16 h = __float2bfloat16(v);
    return *reinterpret_cast<__bf16*>(&h);
}

// ---------------------------------------------------------------------------
// Pipelined dense GEMM: C[m,n] = sum_k A[m,k]*B[n,k] (+bias[n]).
// BM=128, BK=32, 256 threads (4 waves, 2Mx2N), 4 blocks/CU.  K % 32 == 0.
// LDS rows are 32 elements = 4 16B chunks; chunk slot s at row r holds global
// chunk s ^ ((r>>1) & 3)  -> bank-balanced wave64 ds_read_b128.
// EPI: 0 = fp32 +bias (BN=64); 1 = bf16 +bias; 2 = split (gelu->Cv / D2).
// Epilogue reuses the 32KB smem arena for coalesced 16B stores.
// ---------------------------------------------------------------------------
template<int BN, int EPI, bool SHIFT>
__global__ __launch_bounds__(256, 4)
void gemm_mfma(const __hip_bfloat16* __restrict__ A,
               const __hip_bfloat16* __restrict__ B,
               const float* __restrict__ bias,
               void* __restrict__ Cv,
               int K, int lda, int N,
               __hip_bfloat16* __restrict__ D2)
{
    constexpr int NI  = BN / 32;           // n-frags per wave (4 or 2)
    constexpr int BLD = (BN * 4) / 256;    // B cp16 per thread (2 or 1)
    constexpr int NLD = 2 + BLD;           // cp16 per thread per tile
    __shared__ __align__(16) unsigned char smem[32768];
    __bf16* Asb = (__bf16*)smem;            // [2][128*32]
    __bf16* Bsb = (__bf16*)(smem + 16384);  // [2][BN*32]

    const int tid  = threadIdx.x;
    const int lane = tid & 63;
    const int wave = tid >> 6;
    const size_t m0 = (size_t)blockIdx.x * 128;
    const int    n0 = blockIdx.y * BN;
    const int wm = (wave >> 1) * 64;
    const int wn = (wave & 1) * (BN / 2);

    f32x4 acc[4][NI];
#pragma unroll
    for (int i = 0; i < 4; ++i)
#pragma unroll
        for (int j = 0; j < NI; ++j)
            acc[i][j] = f32x4{0.f, 0.f, 0.f, 0.f};

    const int frow = lane & 15;
    const int fq   = lane >> 4;             // chunk index 0..3 within 32-wide row

    auto stage = [&](int buf, int k0) {
        // A tile: 128 rows x 4 chunks = 512 chunks
#pragma unroll
        for (int q = 0; q < 2; ++q) {
            const int lin = q * 256 + tid;
            const int rr  = lin >> 2;
            const int gc  = (lin & 3) ^ ((rr >> 1) & 3);
            const size_t ar = m0 + rr + (SHIFT ? (size_t)(k0 >> 10) : 0);
            const int    ac = SHIFT ? (k0 & 1023) : k0;
            cp16_g2l(A + ar * (size_t)lda + ac + gc * 8, Asb + buf * 4096 + lin * 8);
        }
        // B tile: BN rows x 4 chunks
#pragma unroll
        for (int q = 0; q < BLD; ++q) {
            const int lin = q * 256 + tid;
            const int rr  = lin >> 2;
            const int gc  = (lin & 3) ^ ((rr >> 1) & 3);
            cp16_g2l(B + (size_t)(n0 + rr) * K + k0 + gc * 8,
                     Bsb + buf * (BN * 32) + lin * 8);
        }
    };

    const int nt = K / 32;
    stage(0, 0);
    int cur = 0;
    for (int t = 0; t < nt; ++t) {
        if (t + 1 < nt) {
            stage(cur ^ 1, (t + 1) * 32);
            // wait only for tile t (the NLD loads just issued stay in flight)
            asm volatile("s_waitcnt vmcnt(%0)" :: "n"(NLD) : "memory");
        } else {
            asm volatile("s_waitcnt vmcnt(0)" ::: "memory");
        }
        __builtin_amdgcn_sched_barrier(0);
        __builtin_amdgcn_s_barrier();          // buf[cur] staged for all waves
        __builtin_amdgcn_sched_barrier(0);

        bf16x8 af[4], bfr[NI];
#pragma unroll
        for (int mi = 0; mi < 4; ++mi) {
            const int R = wm + mi * 16 + frow;
            af[mi] = *(const bf16x8*)&Asb[cur * 4096 + R * 32 + ((fq ^ ((R >> 1) & 3)) * 8)];
        }
#pragma unroll
        for (int ni = 0; ni < NI; ++ni) {
            const int R = wn + ni * 16 + frow;
            bfr[ni] = *(const bf16x8*)&Bsb[cur * (BN * 32) + R * 32 + ((fq ^ ((R >> 1) & 3)) * 8)];
        }
        asm volatile("s_waitcnt lgkmcnt(0)" ::: "memory");  // my reads serviced
        __builtin_amdgcn_sched_barrier(0);
        __builtin_amdgcn_s_barrier();          // buf[cur] free for overwrite
        __builtin_amdgcn_sched_barrier(0);

        __builtin_amdgcn_s_setprio(1);
#pragma unroll
        for (int mi = 0; mi < 4; ++mi)
#pragma unroll
            for (int ni = 0; ni < NI; ++ni)
                acc[mi][ni] = __builtin_amdgcn_mfma_f32_16x16x32_bf16(
                    af[mi], bfr[ni], acc[mi][ni], 0, 0, 0);
        __builtin_amdgcn_s_setprio(0);
        cur ^= 1;
    }

    // ---- epilogue: acc -> swizzled LDS -> coalesced 16B/lane global stores.
    // C/D frag layout: col = lane&15, row = (lane>>4)*4 + reg.
    __syncthreads();
    const int er = fq * 4;
    const int ec = frow;

    if (EPI == 0) {
        // fp32 tile 128 x BN(=64): 32 KB = the whole arena.
        float* Cl = (float*)smem;
#pragma unroll
        for (int ni = 0; ni < NI; ++ni) {
            const int cc = wn + ni * 16 + ec;
            const float bv = bias ? bias[n0 + cc] : 0.f;
#pragma unroll
            for (int mi = 0; mi < 4; ++mi)
#pragma unroll
                for (int r2 = 0; r2 < 4; ++r2) {
                    const int R = wm + mi * 16 + er + r2;
                    Cl[R * 64 + ((((cc >> 2) ^ (R & 7)) << 2) | (cc & 3))] =
                        acc[mi][ni][r2] + bv;
                }
        }
        __syncthreads();
        float* outp = (float*)Cv;
#pragma unroll
        for (int p = 0; p < 8; ++p) {
            const int R   = (tid >> 4) + p * 16;
            const int chn = tid & 15;
            const f32x4 v = *(const f32x4*)&Cl[R * 64 + ((chn ^ (R & 7)) << 2)];
            *(f32x4*)&outp[(m0 + R) * (size_t)N + n0 + chn * 4] = v;
        }
    } else {
        // bf16 tile 128 x BN(=128): 32 KB = the whole arena.
        __bf16* Cl = (__bf16*)smem;
        const bool ahalf = (EPI == 2) && (n0 < 1024);   // block-uniform
#pragma unroll
        for (int ni = 0; ni < NI; ++ni) {
            const int cc = wn + ni * 16 + ec;
            const float bv = bias ? bias[n0 + cc] : 0.f;
#pragma unroll
            for (int mi = 0; mi < 4; ++mi)
#pragma unroll
                for (int r2 = 0; r2 < 4; ++r2) {
                    const int R = wm + mi * 16 + er + r2;
                    float v = acc[mi][ni][r2] + bv;
                    if (EPI == 2 && ahalf) v = gelu_tanh(v);
                    Cl[R * 128 + ((((cc >> 3) ^ (R & 7)) << 3) | (cc & 7))] = f2b(v);
                }
        }
        __syncthreads();
#pragma unroll
        for (int p = 0; p < 8; ++p) {
            const int R   = (tid >> 4) + p * 16;
            const int chn = tid & 15;
            const bf16x8 v = *(const bf16x8*)&Cl[R * 128 + ((chn ^ (R & 7)) << 3)];
            if (EPI == 1) {
                *(bf16x8*)((__bf16*)Cv + (m0 + R) * (size_t)N + n0 + chn * 8) = v;
            } else if (n0 < 1024) {
                *(bf16x8*)((__bf16*)Cv + (m0 + R) * 1024 + n0 + chn * 8) = v;
            } else {
                *(bf16x8*)((__bf16*)D2 + (m0 + R + 3) * 1024 + (n0 - 1024) + chn * 8) = v;
            }
        }
    }
}

// ---------------------------------------------------------------------------
// Conv, 64 MFMA/wave per barrier-pair, 2 blocks/CU:
//   bc[t,o] = sum_s sum_i W[o][s*1024+i] * bbp[t+s][i]
// Per kc (32 iters):
//  - B: ALL 4 shift tiles (4 x 128x32 = 32KB) double-buffered, staged at the
//    top of the previous iter (8 cp16/thread), counted vmcnt(8).
//  - A: 132-row halo (8.45KB) single-buffered, staged right after the
//    post-compute barrier (provably free there); covered by the next iter's
//    vmcnt(8) (its 2-3 loads are older than the 8 in-flight B loads).
//  - compute: 4 shifts x 16 MFMA, disjoint LDS regions, NO barriers between
//    shifts; plain C++ ds_reads (compiler's fine-grained lgkmcnt).
// LDS = 8448 + 2*32768 = 73984B -> 2 blocks/CU.
// ---------------------------------------------------------------------------
__global__ __launch_bounds__(256, 2)
void conv_mfma(const __hip_bfloat16* __restrict__ bbp,
               const __hip_bfloat16* __restrict__ W,
               __hip_bfloat16* __restrict__ C)
{
    __shared__ __align__(16) unsigned char smem[73984];
    __bf16* Ah = (__bf16*)smem;             // [132*32] halo, single-buffered
    __bf16* Bt = (__bf16*)(smem + 8448);    // [2][4][128*32] shift tiles

    const int tid  = threadIdx.x;
    const int lane = tid & 63;
    const int wave = tid >> 6;
    const size_t m0 = (size_t)blockIdx.x * 128;
    const int    n0 = blockIdx.y * 128;
    const int wm = (wave >> 1) * 64;
    const int wn = (wave & 1) * 64;

    f32x4 acc[4][4];
#pragma unroll
    for (int i = 0; i < 4; ++i)
#pragma unroll
        for (int j = 0; j < 4; ++j)
            acc[i][j] = f32x4{0.f, 0.f, 0.f, 0.f};

    const int frow = lane & 15;
    const int fq   = lane >> 4;

    auto stageA = [&](int kc) {             // 132 rows x 4 chunks = 528 chunks
#pragma unroll
        for (int q = 0; q < 2; ++q) {
            const int lin = q * 256 + tid;
            const int rr  = lin >> 2;
            const int gc  = (lin & 3) ^ ((rr >> 1) & 3);
            cp16_g2l(bbp + (m0 + rr) * 1024 + kc + gc * 8, Ah + lin * 8);
        }
        if (tid < 16) {
            const int lin = 512 + tid;
            const int rr  = lin >> 2;
            const int gc  = (lin & 3) ^ ((rr >> 1) & 3);
            cp16_g2l(bbp + (m0 + rr) * 1024 + kc + gc * 8, Ah + lin * 8);
        }
    };
    auto stageB = [&](int buf, int kc) {    // 4 shift tiles x 512 chunks
#pragma unroll
        for (int s = 0; s < 4; ++s)
#pragma unroll
            for (int q = 0; q < 2; ++q) {
                const int lin = q * 256 + tid;
                const int rr  = lin >> 2;
                const int gc  = (lin & 3) ^ ((rr >> 1) & 3);
                cp16_g2l(W + (size_t)(n0 + rr) * 4096 + s * 1024 + kc + gc * 8,
                         Bt + buf * 16384 + s * 4096 + lin * 8);
            }
    };

    stageA(0);
    stageB(0, 0);
    int bcur = 0;
    for (int t = 0; t < 32; ++t) {
        if (t + 1 < 32) {
            stageB(bcur ^ 1, (t + 1) * 32);
            // leave exactly the 8 just-issued B loads in flight; everything
            // older (this kc's B + halo) must be complete.
            asm volatile("s_waitcnt vmcnt(8)" ::: "memory");
        } else {
            asm volatile("s_waitcnt vmcnt(0)" ::: "memory");
        }
        __builtin_amdgcn_sched_barrier(0);
        __builtin_amdgcn_s_barrier();          // halo + B[bcur] staged
        __builtin_amdgcn_sched_barrier(0);

        __builtin_amdgcn_s_setprio(1);
#pragma unroll
        for (int s = 0; s < 4; ++s) {
            bf16x8 af[4], bfr[4];
#pragma unroll
            for (int mi = 0; mi < 4; ++mi) {
                const int R = wm + mi * 16 + frow + s;       // shifted halo row
                af[mi] = *(const bf16x8*)&Ah[R * 32 + ((fq ^ ((R >> 1) & 3)) * 8)];
            }
#pragma unroll
            for (int ni = 0; ni < 4; ++ni) {
                const int R = wn + ni * 16 + frow;
                bfr[ni] = *(const bf16x8*)&Bt[bcur * 16384 + s * 4096 + R * 32 +
                                              ((fq ^ ((R >> 1) & 3)) * 8)];
            }
#pragma unroll
            for (int mi = 0; mi < 4; ++mi)
#pragma unroll
                for (int ni = 0; ni < 4; ++ni)
                    acc[mi][ni] = __builtin_amdgcn_mfma_f32_16x16x32_bf16(
                        af[mi], bfr[ni], acc[mi][ni], 0, 0, 0);
        }
        __builtin_amdgcn_s_setprio(0);
        __builtin_amdgcn_sched_barrier(0);
        __builtin_amdgcn_s_barrier();          // halo + B[bcur] free
        __builtin_amdgcn_sched_barrier(0);
        if (t + 1 < 32) stageA((t + 1) * 32);  // halo prefetch into freed buffer
        bcur ^= 1;
    }

    // ---- epilogue: bf16 tile 128x128 via swizzled LDS, coalesced stores.
    __syncthreads();
    const int er = fq * 4;
    const int ec = frow;
    __bf16* Cl = (__bf16*)smem;
#pragma unroll
    for (int ni = 0; ni < 4; ++ni) {
        const int cc = wn + ni * 16 + ec;
#pragma unroll
        for (int mi = 0; mi < 4; ++mi)
#pragma unroll
            for (int r2 = 0; r2 < 4; ++r2) {
                const int R = wm + mi * 16 + er + r2;
                Cl[R * 128 + ((((cc >> 3) ^ (R & 7)) << 3) | (cc & 7))] =
                    f2b(acc[mi][ni][r2]);
            }
    }
    __syncthreads();
#pragma unroll
    for (int p = 0; p < 8; ++p) {
        const int R   = (tid >> 4) + p * 16;
        const int chn = tid & 15;
        const bf16x8 v = *(const bf16x8*)&Cl[R * 128 + ((chn ^ (R & 7)) << 3)];
        *(bf16x8*)((__bf16*)C + (m0 + R) * 1024 + n0 + chn * 8) = v;
    }
}

// One prep kernel: xb, w1b, w_rgb, w_outb conversions + conv repack + bbp pad zero.
#define PREP_X   6291456            // 8192*768
#define PREP_W1  (PREP_X + 1572864) // + 2048*768
#define PREP_WRG (PREP_W1 + 2097152)// + 2048*1024
#define PREP_WO  (PREP_WRG + 786432)// + 768*1024
#define PREP_CW  (PREP_WO + 4194304)// + 1024*4096
#define PREP_TOT (PREP_CW + 3072)   // + pad rows
__global__ void prep_kernel(const float* __restrict__ x, const float* __restrict__ w1,
                            const float* __restrict__ w_rg, const float* __restrict__ w_out,
                            const float* __restrict__ conv_w,
                            __hip_bfloat16* __restrict__ xb, __hip_bfloat16* __restrict__ w1b,
                            __hip_bfloat16* __restrict__ w_rgb, __hip_bfloat16* __restrict__ w_outb,
                            __hip_bfloat16* __restrict__ wbigb, __hip_bfloat16* __restrict__ bbp)
{
    const int idx = blockIdx.x * 256 + threadIdx.x;
    if (idx < PREP_X) {
        xb[idx] = __float2bfloat16(x[idx]);
    } else if (idx < PREP_W1) {
        const int i = idx - PREP_X;  w1b[i] = __float2bfloat16(w1[i]);
    } else if (idx < PREP_WRG) {
        const int i = idx - PREP_W1; w_rgb[i] = __float2bfloat16(w_rg[i]);
    } else if (idx < PREP_WO) {
        const int i = idx - PREP_WRG; w_outb[i] = __float2bfloat16(w_out[i]);
    } else if (idx < PREP_CW) {
        const int n = idx - PREP_WO;
        const int o = n >> 12, r = n & 4095, k = r >> 10, i = r & 1023;
        wbigb[n] = __float2bfloat16(conv_w[o * 4096 + i * 4 + k]);
    } else {
        bbp[idx - PREP_CW] = __float2bfloat16(0.f);
    }
}

// Gates recomputed inline from g_pre (T x 2048 bf16) + bc (bf16):
__global__ void scan_pass1(const __hip_bfloat16* __restrict__ gp,
                           const __hip_bfloat16* __restrict__ bc,
                           const float* __restrict__ Lambda,
                           float* __restrict__ ch, float* __restrict__ ca)
{
    const int c = blockIdx.y * 256 + threadIdx.x;
    const int j = blockIdx.x;
    const float cl = -8.f * log1pf(expf(Lambda[c]));
    float h = 0.f, ap = 1.f;
    const int t0 = j * CL;
    for (int tt = 0; tt < CL; ++tt) {
        const int t = t0 + tt;
        const long gi = (long)t * 2048 + c;
        const float ig = 1.f / (1.f + expf(-__bfloat162float(gp[gi])));
        const float rg = 1.f / (1.f + expf(-__bfloat162float(gp[gi + 1024])));
        const float a  = expf(cl * rg);
        const float gx = sqrtf(fmaxf(0.f, 1.f - a * a)) * ig *
                         __bfloat162float(bc[(long)t * 1024 + c]);
        h  = fmaf(a, h, gx);
        ap *= a;
    }
    ch[j * 1024 + c] = h;
    ca[j * 1024 + c] = ap;
}

__global__ void scan_combine(float* __restrict__ ch, const float* __restrict__ ca)
{
    const int c = blockIdx.x * 256 + threadIdx.x;
    float carry = 0.f;
    for (int j = 0; j < NC; ++j) {
        const float hj = ch[j * 1024 + c];
        const float aj = ca[j * 1024 + c];
        ch[j * 1024 + c] = carry;
        carry = fmaf(aj, carry, hj);
    }
}

// Rescan with carry; z = ab * y -> bf16 (zb aliases bc: same-element RMW per thread).
__global__ void scan_pass2(const __hip_bfloat16* __restrict__ gp, const __hip_bfloat16* bc,
                           const float* __restrict__ Lambda,
                           const float* __restrict__ carry_in,
                           const __hip_bfloat16* __restrict__ ab,
                           __hip_bfloat16* zb)
{
    const int c = blockIdx.y * 256 + threadIdx.x;
    const int j = blockIdx.x;
    const float cl = -8.f * log1pf(expf(Lambda[c]));
    float h = carry_in[j * 1024 + c];
    const int t0 = j * CL;
    for (int tt = 0; tt < CL; ++tt) {
        const int t = t0 + tt;
        const long gi = (long)t * 2048 + c;
        const long bi = (long)t * 1024 + c;
        const float ig = 1.f / (1.f + expf(-__bfloat162float(gp[gi])));
        const float rg = 1.f / (1.f + expf(-__bfloat162float(gp[gi + 1024])));
        const float a  = expf(cl * rg);
        const float gx = sqrtf(fmaxf(0.f, 1.f - a * a)) * ig * __bfloat162float(bc[bi]);
        h = fmaf(a, h, gx);
        zb[bi] = __float2bfloat16(__bfloat162float(ab[bi]) * h);
    }
}

extern "C" void kernel_launch(void* const* d_in, const int* in_sizes, int n_in,
                              void* d_out, int out_size, void* d_ws, size_t ws_size,
                              hipStream_t stream)
{
    const float* x      = (const float*)d_in[0];
    const float* w1     = (const float*)d_in[1];
    const float* b1     = (const float*)d_in[2];
    const float* conv_w = (const float*)d_in[3];
    const float* w_rg   = (const float*)d_in[4];
    const float* b_rg   = (const float*)d_in[5];
    const float* w_out  = (const float*)d_in[6];
    const float* b_out  = (const float*)d_in[7];
    const float* Lambda = (const float*)d_in[8];
    float* out = (float*)d_out;
    (void)in_sizes; (void)n_in; (void)out_size; (void)ws_size;

    // ---- workspace layout (~110 MB) ----
    char* p = (char*)d_ws;
    auto alloc = [&](size_t bytes) { char* r = p; p += (bytes + 255) & ~255ULL; return r; };
    __hip_bfloat16* gpre  = (__hip_bfloat16*)alloc(8192ULL * 2048 * 2); // 32 MB
    __hip_bfloat16* ab    = (__hip_bfloat16*)alloc(8192ULL * 1024 * 2); // 16 MB
    __hip_bfloat16* bbp   = (__hip_bfloat16*)alloc(8200ULL * 1024 * 2); // 16.8 MB
    __hip_bfloat16* bcb   = (__hip_bfloat16*)alloc(8192ULL * 1024 * 2); // 16 MB (later zb)
    __hip_bfloat16* wbigb = (__hip_bfloat16*)alloc(1024ULL * 4096 * 2); // 8 MB
    __hip_bfloat16* xb    = (__hip_bfloat16*)alloc(8192ULL * 768 * 2);  // 12 MB
    __hip_bfloat16* w1b   = (__hip_bfloat16*)alloc(2048ULL * 768 * 2);  // 3 MB
    __hip_bfloat16* w_rgb = (__hip_bfloat16*)alloc(2048ULL * 1024 * 2); // 4 MB
    __hip_bfloat16* w_outb= (__hip_bfloat16*)alloc(768ULL * 1024 * 2);  // 1.5 MB
    float*          chv   = (float*)alloc(NC * 1024ULL * 4);
    float*          cav   = (float*)alloc(NC * 1024ULL * 4);
    __hip_bfloat16* zb    = bcb;   // overlay

    prep_kernel<<<PREP_TOT / 256, 256, 0, stream>>>(x, w1, w_rg, w_out, conv_w,
                                                    xb, w1b, w_rgb, w_outb, wbigb, bbp);

    // h = x @ w1.T + b1, fused split: ab = bf16(gelu), bbp = bf16 (rows +3)
    {
        dim3 grid(T_LEN / 128, 2048 / 128);
        gemm_mfma<128, 2, false><<<grid, 256, 0, stream>>>(xb, w1b, b1, ab, DM, DM, 2048, bbp);
    }

    // bc = causal conv (shift-reuse, 64 MFMA/barrier-pair) -> bf16
    {
        dim3 grid(T_LEN / 128, 1024 / 128);
        conv_mfma<<<grid, 256, 0, stream>>>(bbp, wbigb, bcb);
    }

    // g_pre = bc @ w_rg.T + b_rg -> bf16
    {
        dim3 grid(T_LEN / 128, 2048 / 128);
        gemm_mfma<128, 1, false><<<grid, 256, 0, stream>>>(bcb, w_rgb, b_rg, gpre, DR, DR, 2048, nullptr);
    }

    // chunked scan with fused gates; z = ab*y -> bf16 (overlays bcb)
    {
        dim3 gs(NC, DR / 256);
        scan_pass1<<<gs, 256, 0, stream>>>(gpre, bcb, Lambda, chv, cav);
        scan_combine<<<DR / 256, 256, 0, stream>>>(chv, cav);
        scan_pass2<<<gs, 256, 0, stream>>>(gpre, bcb, Lambda, chv, ab, zb);
    }

    // out = z @ w_out.T + b_out -> fp32
    {
        dim3 grid(T_LEN / 128, DM / 64);
        gemm_mfma<64, 0, false><<<grid, 256, 0, stream>>>(zb, w_outb, b_out, out, DR, DR, DM, nullptr);
    }
}